// Round 1
// baseline (2422.439 us; speedup 1.0000x reference)
//
#include <hip/hip_runtime.h>
#include <hip/hip_fp16.h>

// StackedAttentionModel: 8-layer transformer fwd, S=2048 E=1024 H=16 D=64 F=4096 V=32000.
// Strategy: fp16 MFMA everywhere (fp32 accum), global activation scale CS=2^12
// (exact power of 2, folded out exactly) to keep fp16 values in normal range.

#define SS 2048
#define EE 1024
#define NH 16
#define HD 64
#define FF 4096
#define NV 32000
#define NL 8

typedef _Float16 f16;
typedef _Float16 f16x8 __attribute__((ext_vector_type(8)));
typedef _Float16 f16x4 __attribute__((ext_vector_type(4)));
typedef float f32x4 __attribute__((ext_vector_type(4)));

#define CS 4096.0f          // 2^12 activation scale
#define INV_CS 0.000244140625f
#define SCORE_SCALE 7.450580596923828e-09f  // 1/(8*CS^2) = 2^-27

// async global->LDS, 16B per lane; lds base must be wave-uniform (lane offset is HW-implicit)
__device__ __forceinline__ void gload16(const void* g, void* lds) {
    __builtin_amdgcn_global_load_lds(
        (const __attribute__((address_space(1))) unsigned int*)g,
        (__attribute__((address_space(3))) unsigned int*)lds, 16, 0, 0);
}

// ---------------- embedding gather (fp32 -> fp16 * CS) ----------------
__global__ void k_embed(const int* __restrict__ ids, const float* __restrict__ emb,
                        f16* __restrict__ xh) {
    int s = blockIdx.x;
    int e = threadIdx.x * 4;
    const float4 v = *(const float4*)&emb[(size_t)ids[s] * EE + e];
    f16x4 h;
    h[0] = (f16)(v.x * CS); h[1] = (f16)(v.y * CS);
    h[2] = (f16)(v.z * CS); h[3] = (f16)(v.w * CS);
    *(f16x4*)&xh[(size_t)s * EE + e] = h;
}

// ---------------- transpose + convert fp32 -> fp16 ----------------
// in[R][C] (ldi), out[C][R] (ldo). Grid (C/32, R/32), block (32,32).
__global__ void k_transpose_f32_f16(const float* __restrict__ in, f16* __restrict__ out,
                                    int ldi, int ldo) {
    __shared__ float tile[32][33];
    int bx = blockIdx.x * 32, by = blockIdx.y * 32;
    int tx = threadIdx.x, ty = threadIdx.y;
    tile[ty][tx] = in[(size_t)(by + ty) * ldi + bx + tx];
    __syncthreads();
    out[(size_t)(bx + ty) * ldo + by + tx] = (f16)tile[tx][ty];
}

// fp16 -> fp16 transpose (for V -> V^T)
__global__ void k_transpose_h(const f16* __restrict__ in, f16* __restrict__ out,
                              int ldi, int ldo) {
    __shared__ f16 tile[32][33];
    int bx = blockIdx.x * 32, by = blockIdx.y * 32;
    int tx = threadIdx.x, ty = threadIdx.y;
    tile[ty][tx] = in[(size_t)(by + ty) * ldi + bx + tx];
    __syncthreads();
    out[(size_t)(bx + ty) * ldo + by + tx] = tile[tx][ty];
}

// concat 3 bias vectors of length EE
__global__ void k_concat3(const float* __restrict__ a, const float* __restrict__ b,
                          const float* __restrict__ c, float* __restrict__ o) {
    int i = blockIdx.x * 256 + threadIdx.x;  // 0..3071
    o[i] = i < EE ? a[i] : (i < 2 * EE ? b[i - EE] : c[i - 2 * EE]);
}

// ---------------- GEMM: C[M,N] = A[M,K] * Bt[N,K]^T ----------------
// fp16 in, fp32 accum. 128x128 tile, BK=32, 4 waves (2x2), mfma 16x16x32 f16.
// LDS XOR-swizzle (chunk ^= (row>>1)&3) applied on global SOURCE + ds_read (both sides).
__global__ __launch_bounds__(256) void k_gemm_bt(
    const f16* __restrict__ A, const f16* __restrict__ B,
    const float* __restrict__ bias, f16* __restrict__ Ch, float* __restrict__ Cf,
    int M, int N, int K, float bscale, float oscale, int relu) {
    __shared__ f16 As[128 * 32];
    __shared__ f16 Bs[128 * 32];
    const int t = threadIdx.x;
    const int l = t & 63, w = t >> 6;
    const int m0 = blockIdx.y * 128, n0 = blockIdx.x * 128;
    const int wm = (w >> 1) * 64, wn = (w & 1) * 64;

    f32x4 acc[4][4] = {};

    // staging: thread t covers LDS row srow=t>>2, chunk t&3 (8 halves); source col XOR-swizzled
    const int srow = t >> 2;
    const int scol = 8 * ((t & 3) ^ ((srow >> 1) & 3));
    const size_t a0 = (size_t)(m0 + srow) * K + scol;
    const size_t a1 = (size_t)(m0 + srow + 64) * K + scol;
    const size_t b0 = (size_t)(n0 + srow) * K + scol;
    const size_t b1 = (size_t)(n0 + srow + 64) * K + scol;
    char* ldsA = (char*)As + w * 1024;  // wave-uniform bases
    char* ldsB = (char*)Bs + w * 1024;

    const int lr = l & 15, lc = l >> 4;
    const int rchunk = 8 * (lc ^ ((lr >> 1) & 3));  // swizzled read chunk (halves)

    for (int kt = 0; kt < K; kt += 32) {
        __syncthreads();
        gload16(A + a0 + kt, ldsA);
        gload16(A + a1 + kt, ldsA + 4096);
        gload16(B + b0 + kt, ldsB);
        gload16(B + b1 + kt, ldsB + 4096);
        __syncthreads();

        f16x8 af[4], bf[4];
#pragma unroll
        for (int m = 0; m < 4; m++)
            af[m] = *(const f16x8*)&As[(wm + m * 16 + lr) * 32 + rchunk];
#pragma unroll
        for (int n = 0; n < 4; n++)
            bf[n] = *(const f16x8*)&Bs[(wn + n * 16 + lr) * 32 + rchunk];
#pragma unroll
        for (int m = 0; m < 4; m++)
#pragma unroll
            for (int n = 0; n < 4; n++)
                acc[m][n] = __builtin_amdgcn_mfma_f32_16x16x32_f16(af[m], bf[n], acc[m][n], 0, 0, 0);
    }

    // epilogue: C/D layout col=lane&15, row=(lane>>4)*4+reg
#pragma unroll
    for (int m = 0; m < 4; m++)
#pragma unroll
        for (int n = 0; n < 4; n++)
#pragma unroll
            for (int r = 0; r < 4; r++) {
                int row = m0 + wm + m * 16 + lc * 4 + r;
                int col = n0 + wn + n * 16 + lr;
                float v = acc[m][n][r];
                if (bias) v += bias[col] * bscale;
                if (relu) v = fmaxf(v, 0.0f);
                if (Ch) Ch[(size_t)row * N + col] = (f16)v;
                else    Cf[(size_t)row * N + col] = v * oscale;
            }
}

// ---------------- flash attention ----------------
// grid (H=16, QB=32). Block 256 = 4 waves; wave w owns q-rows q0+16w..+15.
// K,V tiles [64][64] fp16 in LDS, (row&7) XOR-swizzle (both sides). P via swizzled LDS.
__global__ __launch_bounds__(256) void k_flash(
    const f16* __restrict__ qkv, const f16* __restrict__ vt, f16* __restrict__ attn) {
    __shared__ f16 Ks[64 * 64];
    __shared__ f16 Vs[64 * 64];
    __shared__ f16 Ps[4 * 16 * 64];
    const int h = blockIdx.x;
    const int qb = blockIdx.y;
    const int t = threadIdx.x, l = t & 63, w = t >> 6;
    const int lr = l & 15, lc = l >> 4;
    const int q0 = qb * 64;
    const int qrow = q0 + w * 16 + lr;

    // Q fragments (global, read once)
    f16x8 qf0 = *(const f16x8*)&qkv[(size_t)qrow * 3072 + h * 64 + lc * 8];
    f16x8 qf1 = *(const f16x8*)&qkv[(size_t)qrow * 3072 + h * 64 + 32 + lc * 8];

    f32x4 o[4] = {};
    float mrun[4], lrun[4];
#pragma unroll
    for (int r = 0; r < 4; r++) { mrun[r] = -__builtin_inff(); lrun[r] = 0.0f; }

    // staging coords: row = t>>3 (0..31, +32 on 2nd issue), chunk t&7, swizzled source
    const int krow = t >> 3;
    const int kscol = 8 * ((t & 7) ^ (krow & 7));
    const f16* gK = qkv + EE + h * 64;             // K block in qkv
    const f16* gV = vt + (size_t)(h * 64) * SS;    // V^T rows = d
    char* ldsK = (char*)Ks + w * 1024;
    char* ldsV = (char*)Vs + w * 1024;
    f16* Pw = &Ps[w * 16 * 64];
    const int psw = (lr & 7) << 4;   // P/V read swizzle for row=lr

    const int nkt = qb + 1;
    for (int kt = 0; kt < nkt; kt++) {
        const int k0 = kt * 64;
        __syncthreads();
        gload16(gK + (size_t)(k0 + krow) * 3072 + kscol, ldsK);
        gload16(gK + (size_t)(k0 + krow + 32) * 3072 + kscol, ldsK + 4096);
        gload16(gV + (size_t)krow * SS + k0 + kscol, ldsV);
        gload16(gV + (size_t)(krow + 32) * SS + k0 + kscol, ldsV + 4096);
        __syncthreads();

        // QK^T: scores[16q x 64k] per wave
        f32x4 sc[4];
#pragma unroll
        for (int kj = 0; kj < 4; kj++) {
            const int krw = kj * 16 + lr;
            const int sw = krw & 7;
            f16x8 kb0 = *(const f16x8*)&Ks[krw * 64 + 8 * (lc ^ sw)];
            f16x8 kb1 = *(const f16x8*)&Ks[krw * 64 + 8 * ((lc + 4) ^ sw)];
            f32x4 z = {};
            z = __builtin_amdgcn_mfma_f32_16x16x32_f16(qf0, kb0, z, 0, 0, 0);
            z = __builtin_amdgcn_mfma_f32_16x16x32_f16(qf1, kb1, z, 0, 0, 0);
            sc[kj] = z;
        }

        // scale + causal mask (only diagonal tile needs masking)
        const bool diag = (kt == qb);
#pragma unroll
        for (int kj = 0; kj < 4; kj++)
#pragma unroll
            for (int r = 0; r < 4; r++) {
                float v = sc[kj][r] * SCORE_SCALE;
                if (diag) {
                    int qq = w * 16 + lc * 4 + r;
                    int kk = kj * 16 + lr;
                    if (kk > qq) v = -__builtin_inff();
                }
                sc[kj][r] = v;
            }

        // online softmax (rows live in 16-lane groups sharing lc)
#pragma unroll
        for (int r = 0; r < 4; r++) {
            float mt = fmaxf(fmaxf(sc[0][r], sc[1][r]), fmaxf(sc[2][r], sc[3][r]));
            mt = fmaxf(mt, __shfl_xor(mt, 1));
            mt = fmaxf(mt, __shfl_xor(mt, 2));
            mt = fmaxf(mt, __shfl_xor(mt, 4));
            mt = fmaxf(mt, __shfl_xor(mt, 8));
            float mnew = fmaxf(mrun[r], mt);
            float alpha = __expf(mrun[r] - mnew);
            float psum = 0.0f;
#pragma unroll
            for (int kj = 0; kj < 4; kj++) {
                float p = __expf(sc[kj][r] - mnew);
                sc[kj][r] = p;
                psum += p;
            }
            psum += __shfl_xor(psum, 1);
            psum += __shfl_xor(psum, 2);
            psum += __shfl_xor(psum, 4);
            psum += __shfl_xor(psum, 8);
            lrun[r] = lrun[r] * alpha + psum;
            mrun[r] = mnew;
#pragma unroll
            for (int dj = 0; dj < 4; dj++) o[dj][r] *= alpha;
        }

        // P -> fp16 -> swizzled LDS (wave-private region, no barrier needed)
#pragma unroll
        for (int kj = 0; kj < 4; kj++)
#pragma unroll
            for (int r = 0; r < 4; r++) {
                int prow = lc * 4 + r;
                int pb = prow * 128 + ((kj * 16 + lr) * 2 ^ ((prow & 7) << 4));
                *(f16*)((char*)Pw + pb) = (f16)sc[kj][r];
            }

        // PV: O[16q x 64d] += P[16q x 64k] * V[64k x 64d]
#pragma unroll
        for (int s2 = 0; s2 < 2; s2++) {
            f16x8 pa = *(const f16x8*)((const char*)Pw + lr * 128 + (((lc + 4 * s2) * 16) ^ psw));
#pragma unroll
            for (int dj = 0; dj < 4; dj++) {
                const int vrow = dj * 16 + lr;
                f16x8 vb = *(const f16x8*)&Vs[vrow * 64 + 8 * ((lc + 4 * s2) ^ (vrow & 7))];
                o[dj] = __builtin_amdgcn_mfma_f32_16x16x32_f16(pa, vb, o[dj], 0, 0, 0);
            }
        }
    }

    // epilogue: divide by row sum; O is CS-scaled (P unscaled * CS-scaled V) -> store fp16
#pragma unroll
    for (int dj = 0; dj < 4; dj++)
#pragma unroll
        for (int r = 0; r < 4; r++) {
            float v = o[dj][r] / lrun[r];
            attn[(size_t)(q0 + w * 16 + lc * 4 + r) * EE + h * 64 + dj * 16 + lr] = (f16)v;
        }
}

// ---------------- host launch ----------------
extern "C" void kernel_launch(void* const* d_in, const int* in_sizes, int n_in,
                              void* d_out, int out_size, void* d_ws, size_t ws_size,
                              hipStream_t stream) {
    const int*   ids  = (const int*)d_in[0];
    const float* emb  = (const float*)d_in[2];
    const float* Wq   = (const float*)d_in[3];
    const float* bq   = (const float*)d_in[4];
    const float* Wk   = (const float*)d_in[5];
    const float* bk   = (const float*)d_in[6];
    const float* Wv   = (const float*)d_in[7];
    const float* bv   = (const float*)d_in[8];
    const float* W1   = (const float*)d_in[9];
    const float* b1   = (const float*)d_in[10];
    const float* W2   = (const float*)d_in[11];
    const float* b2   = (const float*)d_in[12];
    const float* Wout = (const float*)d_in[13];
    float* out = (float*)d_out;

    // workspace carve-up (all fp16 except bqkv)
    char* p = (char*)d_ws;
    f16* xh    = (f16*)p; p += (size_t)SS * EE * 2;        // 4 MB
    f16* qkvh  = (f16*)p; p += (size_t)SS * 3 * EE * 2;    // 12 MB
    f16* vt    = (f16*)p; p += (size_t)EE * SS * 2;        // 4 MB
    f16* attn  = (f16*)p; p += (size_t)SS * EE * 2;        // 4 MB
    f16* h1    = (f16*)p; p += (size_t)SS * FF * 2;        // 16 MB
    f16* wqkvt = (f16*)p; p += (size_t)3 * EE * EE * 2;    // 6 MB
    f16* w1t   = (f16*)p; p += (size_t)FF * EE * 2;        // 8 MB
    f16* w2t   = (f16*)p; p += (size_t)EE * FF * 2;        // 8 MB
    f16* woutt = (f16*)p; p += (size_t)NV * EE * 2;        // 64 MB
    float* bqkv = (float*)p; p += 3 * EE * 4;

    dim3 b32(32, 32);

    k_embed<<<SS, 256, 0, stream>>>(ids, emb, xh);

    for (int l = 0; l < NL; l++) {
        k_transpose_f32_f16<<<dim3(EE / 32, EE / 32), b32, 0, stream>>>(Wq + (size_t)l * EE * EE, wqkvt, EE, EE);
        k_transpose_f32_f16<<<dim3(EE / 32, EE / 32), b32, 0, stream>>>(Wk + (size_t)l * EE * EE, wqkvt + EE * EE, EE, EE);
        k_transpose_f32_f16<<<dim3(EE / 32, EE / 32), b32, 0, stream>>>(Wv + (size_t)l * EE * EE, wqkvt + 2 * EE * EE, EE, EE);
        k_transpose_f32_f16<<<dim3(FF / 32, EE / 32), b32, 0, stream>>>(W1 + (size_t)l * EE * FF, w1t, FF, EE);
        k_transpose_f32_f16<<<dim3(EE / 32, FF / 32), b32, 0, stream>>>(W2 + (size_t)l * FF * EE, w2t, EE, FF);
        k_concat3<<<12, 256, 0, stream>>>(bq + l * EE, bk + l * EE, bv + l * EE, bqkv);

        // QKV: [2048,1024] x [3072,1024]^T -> qkvh fp16 (CS-scaled)
        k_gemm_bt<<<dim3(3 * EE / 128, SS / 128), 256, 0, stream>>>(
            xh, wqkvt, bqkv, qkvh, nullptr, SS, 3 * EE, EE, CS, 1.0f, 0);

        // V -> V^T [1024][2048]
        k_transpose_h<<<dim3(EE / 32, SS / 32), b32, 0, stream>>>(qkvh + 2 * EE, vt, 3 * EE, SS);

        k_flash<<<dim3(NH, SS / 64), 256, 0, stream>>>(qkvh, vt, attn);

        // FFN1 + relu: [2048,1024] x [4096,1024]^T -> h1
        k_gemm_bt<<<dim3(FF / 128, SS / 128), 256, 0, stream>>>(
            attn, w1t, b1 + (size_t)l * FF, h1, nullptr, SS, FF, EE, CS, 1.0f, 1);

        // FFN2: [2048,4096] x [1024,4096]^T -> xh (next layer input)
        k_gemm_bt<<<dim3(EE / 128, SS / 128), 256, 0, stream>>>(
            h1, w2t, b2 + (size_t)l * EE, xh, nullptr, SS, EE, FF, CS, 1.0f, 0);
    }

    // logits: [2048,1024] x [32000,1024]^T -> d_out fp32, unscale by 1/CS
    k_transpose_f32_f16<<<dim3(NV / 32, EE / 32), b32, 0, stream>>>(Wout, woutt, NV, EE);
    k_gemm_bt<<<dim3(NV / 128, SS / 128), 256, 0, stream>>>(
        xh, woutt, nullptr, nullptr, out, SS, NV, EE, 0.0f, INV_CS, 0);
}

// Round 2
// 1914.358 us; speedup vs baseline: 1.2654x; 1.2654x over previous
//
#include <hip/hip_runtime.h>
#include <hip/hip_fp16.h>

// StackedAttentionModel: 8-layer transformer fwd, S=2048 E=1024 H=16 D=64 F=4096 V=32000.
// fp16 MFMA (fp32 accum), global activation scale CS=2^12 folded out exactly.
// R2: XCD+m-fast grid swizzle, 2-phase double-buffered staging (T3-min), FFN2 split-K=2.

#define SS 2048
#define EE 1024
#define NH 16
#define FF 4096
#define NV 32000
#define NL 8

typedef _Float16 f16;
typedef _Float16 f16x8 __attribute__((ext_vector_type(8)));
typedef _Float16 f16x4 __attribute__((ext_vector_type(4)));
typedef float f32x4 __attribute__((ext_vector_type(4)));

#define CS 4096.0f          // 2^12 activation scale
#define INV_CS 0.000244140625f
#define SCORE_SCALE 7.450580596923828e-09f  // 1/(8*CS^2) = 2^-27

__device__ __forceinline__ void gload16(const void* g, void* lds) {
    __builtin_amdgcn_global_load_lds(
        (const __attribute__((address_space(1))) unsigned int*)g,
        (__attribute__((address_space(3))) unsigned int*)lds, 16, 0, 0);
}

// ---------------- embedding gather (fp32 -> fp16 * CS) ----------------
__global__ void k_embed(const int* __restrict__ ids, const float* __restrict__ emb,
                        f16* __restrict__ xh) {
    int s = blockIdx.x;
    int e = threadIdx.x * 4;
    const float4 v = *(const float4*)&emb[(size_t)ids[s] * EE + e];
    f16x4 h;
    h[0] = (f16)(v.x * CS); h[1] = (f16)(v.y * CS);
    h[2] = (f16)(v.z * CS); h[3] = (f16)(v.w * CS);
    *(f16x4*)&xh[(size_t)s * EE + e] = h;
}

// ---------------- single transpose fp32 -> fp16 (Wout) ----------------
__global__ void k_transpose_f32_f16(const float* __restrict__ in, f16* __restrict__ out,
                                    int ldi, int ldo) {
    __shared__ float tile[32][33];
    int bx = blockIdx.x * 32, by = blockIdx.y * 32;
    int tx = threadIdx.x, ty = threadIdx.y;
    tile[ty][tx] = in[(size_t)(by + ty) * ldi + bx + tx];
    __syncthreads();
    out[(size_t)(bx + ty) * ldo + by + tx] = (f16)tile[tx][ty];
}

// fused per-layer weight transposes: Wq,Wk,Wv (1024x1024 each), W1 (1024x4096), W2 (4096x1024)
__global__ void k_transpose_fused(const float* __restrict__ Wq, const float* __restrict__ Wk,
                                  const float* __restrict__ Wv, const float* __restrict__ W1,
                                  const float* __restrict__ W2,
                                  f16* __restrict__ wqkvt, f16* __restrict__ w1t,
                                  f16* __restrict__ w2t) {
    __shared__ float tile[32][33];
    int b = blockIdx.x;
    const float* in; f16* out; int ldi, ldo, bx, by;
    if (b < 3072) {                       // Wq/Wk/Wv: 1024 tiles each (32x32 grid)
        int s = b >> 10, t2 = b & 1023;
        in = s == 0 ? Wq : (s == 1 ? Wk : Wv);
        out = wqkvt + (size_t)s * EE * EE; ldi = EE; ldo = EE;
        bx = (t2 & 31) * 32; by = (t2 >> 5) * 32;
    } else if (b < 7168) {                // W1 [E,F] -> w1t [F,E]: 128x32 tiles
        int t2 = b - 3072;
        in = W1; out = w1t; ldi = FF; ldo = EE;
        bx = (t2 & 127) * 32; by = (t2 >> 7) * 32;
    } else {                              // W2 [F,E] -> w2t [E,F]: 32x128 tiles
        int t2 = b - 7168;
        in = W2; out = w2t; ldi = EE; ldo = FF;
        bx = (t2 & 31) * 32; by = (t2 >> 5) * 32;
    }
    int tx = threadIdx.x, ty = threadIdx.y;
    tile[ty][tx] = in[(size_t)(by + ty) * ldi + bx + tx];
    __syncthreads();
    out[(size_t)(bx + ty) * ldo + by + tx] = (f16)tile[tx][ty];
}

// fp16 -> fp16 transpose (V -> V^T)
__global__ void k_transpose_h(const f16* __restrict__ in, f16* __restrict__ out,
                              int ldi, int ldo) {
    __shared__ f16 tile[32][33];
    int bx = blockIdx.x * 32, by = blockIdx.y * 32;
    int tx = threadIdx.x, ty = threadIdx.y;
    tile[ty][tx] = in[(size_t)(by + ty) * ldi + bx + tx];
    __syncthreads();
    out[(size_t)(bx + ty) * ldo + by + tx] = tile[tx][ty];
}

__global__ void k_concat3(const float* __restrict__ a, const float* __restrict__ b,
                          const float* __restrict__ c, float* __restrict__ o) {
    int i = blockIdx.x * 256 + threadIdx.x;
    o[i] = i < EE ? a[i] : (i < 2 * EE ? b[i - EE] : c[i - 2 * EE]);
}

// split-K combiner: out = f16(p0 + p1 + bias*CS)
__global__ void k_combine2(const float* __restrict__ p0, const float* __restrict__ p1,
                           const float* __restrict__ bias, f16* __restrict__ out) {
    int i = (blockIdx.x * 256 + threadIdx.x) * 4;
    float4 a = *(const float4*)&p0[i];
    float4 b = *(const float4*)&p1[i];
    float4 bb = *(const float4*)&bias[i & (EE - 1)];
    f16x4 h;
    h[0] = (f16)(a.x + b.x + bb.x * CS); h[1] = (f16)(a.y + b.y + bb.y * CS);
    h[2] = (f16)(a.z + b.z + bb.z * CS); h[3] = (f16)(a.w + b.w + bb.w * CS);
    *(f16x4*)&out[i] = h;
}

// ---------------- GEMM: C[M,N] = A[M,K] * Bt[N,K]^T ----------------
// 128x128 tile, BK=32, 4 waves, mfma 16x16x32 f16, 2-phase dbuf staging,
// bijective XCD swizzle + m-fast decode, optional split-K (kch chunks of Ksub).
__global__ __launch_bounds__(256) void k_gemm_bt(
    const f16* __restrict__ A, const f16* __restrict__ B,
    const float* __restrict__ bias, f16* __restrict__ Ch, float* __restrict__ Cf,
    int M, int N, int Kstride, int Ksub, int nm, int nn, int kch,
    float bscale, float oscale, int relu) {
    __shared__ f16 As[2][4096];
    __shared__ f16 Bs[2][4096];
    const int t = threadIdx.x;
    const int l = t & 63, w = t >> 6;

    // bid -> bijective XCD swizzle -> wgid; m-fast so consecutive wgid share B-panel
    const int nwg = nm * nn * kch;
    const int q8 = nwg >> 3, r8 = nwg & 7;
    const int xcd = blockIdx.x & 7, lid = blockIdx.x >> 3;
    const int wgid = (xcd < r8 ? xcd * (q8 + 1) : r8 * (q8 + 1) + (xcd - r8) * q8) + lid;
    const int kc = wgid / (nm * nn);
    const int rem = wgid - kc * (nm * nn);
    const int m0 = (rem % nm) * 128, n0 = (rem / nm) * 128;

    const f16* Ab = A + (size_t)kc * Ksub;
    const f16* Bb = B + (size_t)kc * Ksub;
    float* Cfb = Cf ? Cf + (size_t)kc * M * N : nullptr;

    const int wm = (w >> 1) * 64, wn = (w & 1) * 64;
    f32x4 acc[4][4] = {};

    // staging: thread t -> LDS row srow=t>>2, chunk t&3; source col XOR-swizzled (both-sides rule)
    const int srow = t >> 2;
    const int scol = 8 * ((t & 3) ^ ((srow >> 1) & 3));
    const size_t a0 = (size_t)(m0 + srow) * Kstride + scol;
    const size_t a1 = (size_t)(m0 + srow + 64) * Kstride + scol;
    const size_t b0 = (size_t)(n0 + srow) * Kstride + scol;
    const size_t b1 = (size_t)(n0 + srow + 64) * Kstride + scol;

    const int lr = l & 15, lc = l >> 4;
    const int rchunk = 8 * (lc ^ ((lr >> 1) & 3));

#define GSTAGE(bb, kt) { \
    char* dA = (char*)As[bb] + w * 1024; \
    char* dB = (char*)Bs[bb] + w * 1024; \
    gload16(Ab + a0 + (kt), dA); \
    gload16(Ab + a1 + (kt), dA + 4096); \
    gload16(Bb + b0 + (kt), dB); \
    gload16(Bb + b1 + (kt), dB + 4096); }

    GSTAGE(0, 0);
    __syncthreads();
    int bsel = 0;
    for (int kt = 0; kt < Ksub; kt += 32) {
        if (kt + 32 < Ksub) GSTAGE(bsel ^ 1, kt + 32);   // prefetch overlaps compute
        f16x8 af[4], bf[4];
#pragma unroll
        for (int m = 0; m < 4; m++)
            af[m] = *(const f16x8*)&As[bsel][(wm + m * 16 + lr) * 32 + rchunk];
#pragma unroll
        for (int n = 0; n < 4; n++)
            bf[n] = *(const f16x8*)&Bs[bsel][(wn + n * 16 + lr) * 32 + rchunk];
#pragma unroll
        for (int m = 0; m < 4; m++)
#pragma unroll
            for (int n = 0; n < 4; n++)
                acc[m][n] = __builtin_amdgcn_mfma_f32_16x16x32_f16(af[m], bf[n], acc[m][n], 0, 0, 0);
        __syncthreads();   // drains vmcnt (prefetch landed) + all waves done reading bsel
        bsel ^= 1;
    }
#undef GSTAGE

    // epilogue: C/D layout col=lane&15, row=(lane>>4)*4+reg
#pragma unroll
    for (int m = 0; m < 4; m++)
#pragma unroll
        for (int n = 0; n < 4; n++)
#pragma unroll
            for (int r = 0; r < 4; r++) {
                int row = m0 + wm + m * 16 + lc * 4 + r;
                int col = n0 + wn + n * 16 + lr;
                float v = acc[m][n][r];
                if (bias) v += bias[col] * bscale;
                if (relu) v = fmaxf(v, 0.0f);
                if (Ch) Ch[(size_t)row * N + col] = (f16)v;
                else    Cfb[(size_t)row * N + col] = v * oscale;
            }
}

// ---------------- flash attention ----------------
// grid (H, S/64). 4 waves x 16 q-rows. K/V double-buffered, 2-phase staging.
__global__ __launch_bounds__(256) void k_flash(
    const f16* __restrict__ qkv, const f16* __restrict__ vt, f16* __restrict__ attn) {
    __shared__ f16 Ks[2][4096];
    __shared__ f16 Vs[2][4096];
    __shared__ f16 Ps[4096];
    const int h = blockIdx.x;
    const int qb = blockIdx.y;
    const int t = threadIdx.x, l = t & 63, w = t >> 6;
    const int lr = l & 15, lc = l >> 4;
    const int q0 = qb * 64;
    const int qrow = q0 + w * 16 + lr;

    f16x8 qf0 = *(const f16x8*)&qkv[(size_t)qrow * 3072 + h * 64 + lc * 8];
    f16x8 qf1 = *(const f16x8*)&qkv[(size_t)qrow * 3072 + h * 64 + 32 + lc * 8];

    f32x4 o[4] = {};
    float mrun[4], lrun[4];
#pragma unroll
    for (int r = 0; r < 4; r++) { mrun[r] = -__builtin_inff(); lrun[r] = 0.0f; }

    const int krow = t >> 3;
    const int kscol = 8 * ((t & 7) ^ (krow & 7));
    const f16* gK = qkv + EE + h * 64;
    const f16* gV = vt + (size_t)(h * 64) * SS;
    f16* Pw = &Ps[w * 16 * 64];
    const int psw = (lr & 7) << 4;

#define FSTAGE(bb, k0) { \
    char* dK = (char*)Ks[bb] + w * 1024; \
    char* dV = (char*)Vs[bb] + w * 1024; \
    gload16(gK + (size_t)((k0) + krow) * 3072 + kscol, dK); \
    gload16(gK + (size_t)((k0) + krow + 32) * 3072 + kscol, dK + 4096); \
    gload16(gV + (size_t)krow * SS + (k0) + kscol, dV); \
    gload16(gV + (size_t)(krow + 32) * SS + (k0) + kscol, dV + 4096); }

    const int nkt = qb + 1;
    FSTAGE(0, 0);
    __syncthreads();
    int bsel = 0;
    for (int kt = 0; kt < nkt; kt++) {
        if (kt + 1 < nkt) FSTAGE(bsel ^ 1, (kt + 1) * 64);

        // QK^T: scores[16q x 64k] per wave
        f32x4 sc[4];
#pragma unroll
        for (int kj = 0; kj < 4; kj++) {
            const int krw = kj * 16 + lr;
            const int sw = krw & 7;
            f16x8 kb0 = *(const f16x8*)&Ks[bsel][krw * 64 + 8 * (lc ^ sw)];
            f16x8 kb1 = *(const f16x8*)&Ks[bsel][krw * 64 + 8 * ((lc + 4) ^ sw)];
            f32x4 z = {};
            z = __builtin_amdgcn_mfma_f32_16x16x32_f16(qf0, kb0, z, 0, 0, 0);
            z = __builtin_amdgcn_mfma_f32_16x16x32_f16(qf1, kb1, z, 0, 0, 0);
            sc[kj] = z;
        }

        const bool diag = (kt == qb);
#pragma unroll
        for (int kj = 0; kj < 4; kj++)
#pragma unroll
            for (int r = 0; r < 4; r++) {
                float v = sc[kj][r] * SCORE_SCALE;
                if (diag) {
                    int qq = w * 16 + lc * 4 + r;   // local q within wave's 16 rows? (see note)
                    int kk = kj * 16 + lr;
                    if (kk > qq) v = -__builtin_inff();
                }
                sc[kj][r] = v;
            }

        // online softmax (rows live in 16-lane groups sharing lc)
#pragma unroll
        for (int r = 0; r < 4; r++) {
            float mt = fmaxf(fmaxf(sc[0][r], sc[1][r]), fmaxf(sc[2][r], sc[3][r]));
            mt = fmaxf(mt, __shfl_xor(mt, 1));
            mt = fmaxf(mt, __shfl_xor(mt, 2));
            mt = fmaxf(mt, __shfl_xor(mt, 4));
            mt = fmaxf(mt, __shfl_xor(mt, 8));
            float mnew = fmaxf(mrun[r], mt);
            float alpha = __expf(mrun[r] - mnew);
            float psum = 0.0f;
#pragma unroll
            for (int kj = 0; kj < 4; kj++) {
                float p = __expf(sc[kj][r] - mnew);
                sc[kj][r] = p;
                psum += p;
            }
            psum += __shfl_xor(psum, 1);
            psum += __shfl_xor(psum, 2);
            psum += __shfl_xor(psum, 4);
            psum += __shfl_xor(psum, 8);
            lrun[r] = lrun[r] * alpha + psum;
            mrun[r] = mnew;
#pragma unroll
            for (int dj = 0; dj < 4; dj++) o[dj][r] *= alpha;
        }

        // P -> fp16 -> swizzled LDS (wave-private region)
#pragma unroll
        for (int kj = 0; kj < 4; kj++)
#pragma unroll
            for (int r = 0; r < 4; r++) {
                int prow = lc * 4 + r;
                int pb = prow * 128 + ((kj * 16 + lr) * 2 ^ ((prow & 7) << 4));
                *(f16*)((char*)Pw + pb) = (f16)sc[kj][r];
            }

        // PV: O[16q x 64d] += P[16q x 64k] * V[64k x 64d]
#pragma unroll
        for (int s2 = 0; s2 < 2; s2++) {
            f16x8 pa = *(const f16x8*)((const char*)Pw + lr * 128 + (((lc + 4 * s2) * 16) ^ psw));
#pragma unroll
            for (int dj = 0; dj < 4; dj++) {
                const int vrow = dj * 16 + lr;
                f16x8 vb = *(const f16x8*)&Vs[bsel][vrow * 64 + 8 * ((lc + 4 * s2) ^ (vrow & 7))];
                o[dj] = __builtin_amdgcn_mfma_f32_16x16x32_f16(pa, vb, o[dj], 0, 0, 0);
            }
        }
        __syncthreads();
        bsel ^= 1;
    }
#undef FSTAGE

#pragma unroll
    for (int dj = 0; dj < 4; dj++)
#pragma unroll
        for (int r = 0; r < 4; r++) {
            float v = o[dj][r] / lrun[r];
            attn[(size_t)(q0 + w * 16 + lc * 4 + r) * EE + h * 64 + dj * 16 + lr] = (f16)v;
        }
}

// ---------------- host launch ----------------
extern "C" void kernel_launch(void* const* d_in, const int* in_sizes, int n_in,
                              void* d_out, int out_size, void* d_ws, size_t ws_size,
                              hipStream_t stream) {
    const int*   ids  = (const int*)d_in[0];
    const float* emb  = (const float*)d_in[2];
    const float* Wq   = (const float*)d_in[3];
    const float* bq   = (const float*)d_in[4];
    const float* Wk   = (const float*)d_in[5];
    const float* bk   = (const float*)d_in[6];
    const float* Wv   = (const float*)d_in[7];
    const float* bv   = (const float*)d_in[8];
    const float* W1   = (const float*)d_in[9];
    const float* b1   = (const float*)d_in[10];
    const float* W2   = (const float*)d_in[11];
    const float* b2   = (const float*)d_in[12];
    const float* Wout = (const float*)d_in[13];
    float* out = (float*)d_out;

    char* p = (char*)d_ws;
    f16* xh    = (f16*)p; p += (size_t)SS * EE * 2;        // 4 MB
    f16* qkvh  = (f16*)p; p += (size_t)SS * 3 * EE * 2;    // 12 MB
    f16* vt    = (f16*)p; p += (size_t)EE * SS * 2;        // 4 MB
    f16* attn  = (f16*)p; p += (size_t)SS * EE * 2;        // 4 MB
    f16* h1    = (f16*)p; p += (size_t)SS * FF * 2;        // 16 MB
    f16* wqkvt = (f16*)p; p += (size_t)3 * EE * EE * 2;    // 6 MB
    f16* w1t   = (f16*)p; p += (size_t)FF * EE * 2;        // 8 MB
    f16* w2t   = (f16*)p; p += (size_t)EE * FF * 2;        // 8 MB
    f16* woutt = (f16*)p; p += (size_t)NV * EE * 2;        // 64 MB
    float* part = (float*)p; p += (size_t)2 * SS * EE * 4; // 16 MB (split-K partials)
    float* bqkv = (float*)p; p += 3 * EE * 4;

    dim3 b32(32, 32);

    k_embed<<<SS, 256, 0, stream>>>(ids, emb, xh);

    for (int l = 0; l < NL; l++) {
        k_transpose_fused<<<11264, b32, 0, stream>>>(
            Wq + (size_t)l * EE * EE, Wk + (size_t)l * EE * EE, Wv + (size_t)l * EE * EE,
            W1 + (size_t)l * EE * FF, W2 + (size_t)l * FF * EE, wqkvt, w1t, w2t);
        k_concat3<<<12, 256, 0, stream>>>(bq + l * EE, bk + l * EE, bv + l * EE, bqkv);

        // QKV: [2048,1024] x [3072,1024]^T -> qkvh fp16 (CS-scaled). grid 16*24
        k_gemm_bt<<<16 * 24, 256, 0, stream>>>(
            xh, wqkvt, bqkv, qkvh, nullptr, SS, 3 * EE, EE, EE, 16, 24, 1, CS, 1.0f, 0);

        k_transpose_h<<<dim3(EE / 32, SS / 32), b32, 0, stream>>>(qkvh + 2 * EE, vt, 3 * EE, SS);

        k_flash<<<dim3(NH, SS / 64), 256, 0, stream>>>(qkvh, vt, attn);

        // FFN1 + relu: [2048,1024] x [4096,1024]^T -> h1. grid 16*32
        k_gemm_bt<<<16 * 32, 256, 0, stream>>>(
            attn, w1t, b1 + (size_t)l * FF, h1, nullptr, SS, FF, EE, EE, 16, 32, 1, CS, 1.0f, 1);

        // FFN2 split-K=2: [2048,4096] x [1024,4096]^T -> fp32 partials. grid 16*8*2
        k_gemm_bt<<<16 * 8 * 2, 256, 0, stream>>>(
            h1, w2t, nullptr, nullptr, part, SS, EE, FF, FF / 2, 16, 8, 2, 0.0f, 1.0f, 0);
        k_combine2<<<SS * EE / 1024, 256, 0, stream>>>(
            part, part + (size_t)SS * EE, b2 + (size_t)l * EE, xh);
    }

    // logits: [2048,1024] x [32000,1024]^T -> fp32 out, unscale 1/CS. grid 16*250
    k_transpose_f32_f16<<<dim3(NV / 32, EE / 32), b32, 0, stream>>>(Wout, woutt, NV, EE);
    k_gemm_bt<<<16 * 250, 256, 0, stream>>>(
        xh, woutt, nullptr, nullptr, out, SS, NV, EE, EE, 16, 250, 1, 0.0f, INV_CS, 0);
}

// Round 3
// 1856.766 us; speedup vs baseline: 1.3047x; 1.0310x over previous
//
#include <hip/hip_runtime.h>
#include <hip/hip_fp16.h>

// StackedAttentionModel: 8-layer transformer fwd, S=2048 E=1024 H=16 D=64 F=4096 V=32000.
// fp16 MFMA (fp32 accum), global activation scale CS=2^12 folded out exactly.
// R3: counted-vmcnt raw-barrier pipeline (T3+T4) in a new 256-row GEMM (logits/QKV/FFN1)
//     and in flash; T5 setprio; FFN2 stays on the 128^2 split-K kernel.

#define SS 2048
#define EE 1024
#define NH 16
#define FF 4096
#define NV 32000
#define NL 8

typedef _Float16 f16;
typedef _Float16 f16x8 __attribute__((ext_vector_type(8)));
typedef _Float16 f16x4 __attribute__((ext_vector_type(4)));
typedef float f32x4 __attribute__((ext_vector_type(4)));

#define CS 4096.0f          // 2^12 activation scale
#define INV_CS 0.000244140625f
#define SCORE_SCALE 7.450580596923828e-09f  // 1/(8*CS^2) = 2^-27

__device__ __forceinline__ void gload16(const void* g, void* lds) {
    __builtin_amdgcn_global_load_lds(
        (const __attribute__((address_space(1))) unsigned int*)g,
        (__attribute__((address_space(3))) unsigned int*)lds, 16, 0, 0);
}

// ---------------- embedding gather (fp32 -> fp16 * CS) ----------------
__global__ void k_embed(const int* __restrict__ ids, const float* __restrict__ emb,
                        f16* __restrict__ xh) {
    int s = blockIdx.x;
    int e = threadIdx.x * 4;
    const float4 v = *(const float4*)&emb[(size_t)ids[s] * EE + e];
    f16x4 h;
    h[0] = (f16)(v.x * CS); h[1] = (f16)(v.y * CS);
    h[2] = (f16)(v.z * CS); h[3] = (f16)(v.w * CS);
    *(f16x4*)&xh[(size_t)s * EE + e] = h;
}

// ---------------- single transpose fp32 -> fp16 (Wout) ----------------
__global__ void k_transpose_f32_f16(const float* __restrict__ in, f16* __restrict__ out,
                                    int ldi, int ldo) {
    __shared__ float tile[32][33];
    int bx = blockIdx.x * 32, by = blockIdx.y * 32;
    int tx = threadIdx.x, ty = threadIdx.y;
    tile[ty][tx] = in[(size_t)(by + ty) * ldi + bx + tx];
    __syncthreads();
    out[(size_t)(bx + ty) * ldo + by + tx] = (f16)tile[tx][ty];
}

// fused per-layer weight transposes: Wq,Wk,Wv, W1, W2
__global__ void k_transpose_fused(const float* __restrict__ Wq, const float* __restrict__ Wk,
                                  const float* __restrict__ Wv, const float* __restrict__ W1,
                                  const float* __restrict__ W2,
                                  f16* __restrict__ wqkvt, f16* __restrict__ w1t,
                                  f16* __restrict__ w2t) {
    __shared__ float tile[32][33];
    int b = blockIdx.x;
    const float* in; f16* out; int ldi, ldo, bx, by;
    if (b < 3072) {
        int s = b >> 10, t2 = b & 1023;
        in = s == 0 ? Wq : (s == 1 ? Wk : Wv);
        out = wqkvt + (size_t)s * EE * EE; ldi = EE; ldo = EE;
        bx = (t2 & 31) * 32; by = (t2 >> 5) * 32;
    } else if (b < 7168) {
        int t2 = b - 3072;
        in = W1; out = w1t; ldi = FF; ldo = EE;
        bx = (t2 & 127) * 32; by = (t2 >> 7) * 32;
    } else {
        int t2 = b - 7168;
        in = W2; out = w2t; ldi = EE; ldo = FF;
        bx = (t2 & 31) * 32; by = (t2 >> 5) * 32;
    }
    int tx = threadIdx.x, ty = threadIdx.y;
    tile[ty][tx] = in[(size_t)(by + ty) * ldi + bx + tx];
    __syncthreads();
    out[(size_t)(bx + ty) * ldo + by + tx] = (f16)tile[tx][ty];
}

// fp16 -> fp16 transpose (V -> V^T)
__global__ void k_transpose_h(const f16* __restrict__ in, f16* __restrict__ out,
                              int ldi, int ldo) {
    __shared__ f16 tile[32][33];
    int bx = blockIdx.x * 32, by = blockIdx.y * 32;
    int tx = threadIdx.x, ty = threadIdx.y;
    tile[ty][tx] = in[(size_t)(by + ty) * ldi + bx + tx];
    __syncthreads();
    out[(size_t)(bx + ty) * ldo + by + tx] = tile[tx][ty];
}

__global__ void k_concat3(const float* __restrict__ a, const float* __restrict__ b,
                          const float* __restrict__ c, float* __restrict__ o) {
    int i = blockIdx.x * 256 + threadIdx.x;
    o[i] = i < EE ? a[i] : (i < 2 * EE ? b[i - EE] : c[i - 2 * EE]);
}

// split-K combiner: out = f16(p0 + p1 + bias*CS)
__global__ void k_combine2(const float* __restrict__ p0, const float* __restrict__ p1,
                           const float* __restrict__ bias, f16* __restrict__ out) {
    int i = (blockIdx.x * 256 + threadIdx.x) * 4;
    float4 a = *(const float4*)&p0[i];
    float4 b = *(const float4*)&p1[i];
    float4 bb = *(const float4*)&bias[i & (EE - 1)];
    f16x4 h;
    h[0] = (f16)(a.x + b.x + bb.x * CS); h[1] = (f16)(a.y + b.y + bb.y * CS);
    h[2] = (f16)(a.z + b.z + bb.z * CS); h[3] = (f16)(a.w + b.w + bb.w * CS);
    *(f16x4*)&out[i] = h;
}

// ================= 256-row GEMM, counted-vmcnt pipeline =================
// C[M,N] = A[M,K] * B[N,K]^T. BM=256, BK=64, 8 waves.
// BN=256: waves 2x4, wave tile 128x64 (MR=8). BN=128: waves 4x2, wave tile 64x64 (MR=4).
// LDS dbuf; both-sides XOR swizzle (chunk ^= row&7 within 128B rows).
// Pipeline: issue reads -> MFMA -> s_barrier -> stage tile t+2 -> vmcnt(LPT) -> s_barrier.
template<int BN>
__global__ __launch_bounds__(512, 2) void k_gemm256(
    const f16* __restrict__ A, const f16* __restrict__ B,
    const float* __restrict__ bias, f16* __restrict__ Ch, float* __restrict__ Cf,
    int M, int N, int Kstride, int Ksub, int nm, int nn, int kch,
    float bscale, float oscale, int relu) {
    constexpr int WN = (BN == 256) ? 4 : 2;
    constexpr int MR = (BN == 256) ? 8 : 4;     // wave tile rows / 16
    constexpr int BCALLS = BN / 64;             // B stage calls per tile
    constexpr int LPT = 4 + BCALLS;             // loads/tile per wave

    __shared__ f16 As[2][256 * 64];
    __shared__ f16 Bs[2][BN * 64];

    const int t = threadIdx.x;
    const int l = t & 63, w = t >> 6;
    const int lr = l & 15, lc = l >> 4;

    const int nwg = nm * nn * kch;
    const int q8 = nwg >> 3, r8 = nwg & 7;
    const int xcd = blockIdx.x & 7, lid = blockIdx.x >> 3;
    const int wgid = (xcd < r8 ? xcd * (q8 + 1) : r8 * (q8 + 1) + (xcd - r8) * q8) + lid;
    const int kc = wgid / (nm * nn);
    const int rem = wgid - kc * (nm * nn);
    const int m0 = (rem % nm) * 256, n0 = (rem / nm) * BN;

    const f16* Ab = A + (size_t)kc * Ksub;
    const f16* Bb = B + (size_t)kc * Ksub;
    float* Cfb = Cf ? Cf + (size_t)kc * M * N : nullptr;

    const int wr = w / WN, wc = w % WN;

    f32x4 acc[MR][4] = {};

    // staging coords: call c covers rows c*64 + (t>>3); source col-chunk XOR-swizzled
    const int srow = t >> 3;
    const int scol = 8 * ((t & 7) ^ (srow & 7));
    const int NT = Ksub / 64;

#define STAGE(bb, tt_) { \
    const size_t kof = (size_t)(tt_) * 64 + scol; \
    _Pragma("unroll") \
    for (int c = 0; c < 4; c++) \
        gload16(Ab + (size_t)(m0 + c * 64 + srow) * Kstride + kof, \
                (char*)As[bb] + c * 8192 + w * 1024); \
    _Pragma("unroll") \
    for (int c = 0; c < BCALLS; c++) \
        gload16(Bb + (size_t)(n0 + c * 64 + srow) * Kstride + kof, \
                (char*)Bs[bb] + c * 8192 + w * 1024); }

    STAGE(0, 0)
    STAGE(1, 1)
    asm volatile("s_waitcnt vmcnt(%0)" :: "n"(LPT) : "memory");
    __builtin_amdgcn_s_barrier();

    int cur = 0;
    for (int tt = 0; tt < NT; ++tt) {
        const f16* pA = As[cur];
        const f16* pB = Bs[cur];
#pragma unroll
        for (int ks = 0; ks < 2; ks++) {
            f16x8 af[MR], bf[4];
#pragma unroll
            for (int m = 0; m < MR; m++) {
                int row = wr * (MR * 16) + m * 16 + lr;
                af[m] = *(const f16x8*)&pA[row * 64 + 8 * ((ks * 4 + lc) ^ (row & 7))];
            }
#pragma unroll
            for (int n = 0; n < 4; n++) {
                int row = wc * 64 + n * 16 + lr;
                bf[n] = *(const f16x8*)&pB[row * 64 + 8 * ((ks * 4 + lc) ^ (row & 7))];
            }
            __builtin_amdgcn_s_setprio(1);
#pragma unroll
            for (int m = 0; m < MR; m++)
#pragma unroll
                for (int n = 0; n < 4; n++)
                    acc[m][n] = __builtin_amdgcn_mfma_f32_16x16x32_f16(af[m], bf[n], acc[m][n], 0, 0, 0);
            __builtin_amdgcn_s_setprio(0);
        }
        asm volatile("" ::: "memory");
        __builtin_amdgcn_s_barrier();        // all waves done reading buf[cur]
        if (tt + 2 < NT) {
            STAGE(cur, tt + 2)               // overwrite freed buffer; loads span next iter
            asm volatile("s_waitcnt vmcnt(%0)" :: "n"(LPT) : "memory");  // tile tt+1 landed
        } else if (tt + 1 < NT) {
            asm volatile("s_waitcnt vmcnt(0)" ::: "memory");
        }
        __builtin_amdgcn_s_barrier();
        cur ^= 1;
    }
#undef STAGE

#pragma unroll
    for (int m = 0; m < MR; m++)
#pragma unroll
        for (int n = 0; n < 4; n++)
#pragma unroll
            for (int r = 0; r < 4; r++) {
                int row = m0 + wr * (MR * 16) + m * 16 + lc * 4 + r;
                int col = n0 + wc * 64 + n * 16 + lr;
                float v = acc[m][n][r];
                if (bias) v += bias[col] * bscale;
                if (relu) v = fmaxf(v, 0.0f);
                if (Ch) Ch[(size_t)row * N + col] = (f16)v;
                else    Cfb[(size_t)row * N + col] = v * oscale;
            }
}

// ---------------- 128^2 GEMM (kept for FFN2 split-K) ----------------
__global__ __launch_bounds__(256) void k_gemm_bt(
    const f16* __restrict__ A, const f16* __restrict__ B,
    const float* __restrict__ bias, f16* __restrict__ Ch, float* __restrict__ Cf,
    int M, int N, int Kstride, int Ksub, int nm, int nn, int kch,
    float bscale, float oscale, int relu) {
    __shared__ f16 As[2][4096];
    __shared__ f16 Bs[2][4096];
    const int t = threadIdx.x;
    const int l = t & 63, w = t >> 6;

    const int nwg = nm * nn * kch;
    const int q8 = nwg >> 3, r8 = nwg & 7;
    const int xcd = blockIdx.x & 7, lid = blockIdx.x >> 3;
    const int wgid = (xcd < r8 ? xcd * (q8 + 1) : r8 * (q8 + 1) + (xcd - r8) * q8) + lid;
    const int kc = wgid / (nm * nn);
    const int rem = wgid - kc * (nm * nn);
    const int m0 = (rem % nm) * 128, n0 = (rem / nm) * 128;

    const f16* Ab = A + (size_t)kc * Ksub;
    const f16* Bb = B + (size_t)kc * Ksub;
    float* Cfb = Cf ? Cf + (size_t)kc * M * N : nullptr;

    const int wm = (w >> 1) * 64, wn = (w & 1) * 64;
    f32x4 acc[4][4] = {};

    const int srow = t >> 2;
    const int scol = 8 * ((t & 3) ^ ((srow >> 1) & 3));
    const size_t a0 = (size_t)(m0 + srow) * Kstride + scol;
    const size_t a1 = (size_t)(m0 + srow + 64) * Kstride + scol;
    const size_t b0 = (size_t)(n0 + srow) * Kstride + scol;
    const size_t b1 = (size_t)(n0 + srow + 64) * Kstride + scol;

    const int lr = l & 15, lc = l >> 4;
    const int rchunk = 8 * (lc ^ ((lr >> 1) & 3));

#define GSTAGE(bb, kt) { \
    char* dA = (char*)As[bb] + w * 1024; \
    char* dB = (char*)Bs[bb] + w * 1024; \
    gload16(Ab + a0 + (kt), dA); \
    gload16(Ab + a1 + (kt), dA + 4096); \
    gload16(Bb + b0 + (kt), dB); \
    gload16(Bb + b1 + (kt), dB + 4096); }

    GSTAGE(0, 0);
    __syncthreads();
    int bsel = 0;
    for (int kt = 0; kt < Ksub; kt += 32) {
        if (kt + 32 < Ksub) GSTAGE(bsel ^ 1, kt + 32);
        f16x8 af[4], bf[4];
#pragma unroll
        for (int m = 0; m < 4; m++)
            af[m] = *(const f16x8*)&As[bsel][(wm + m * 16 + lr) * 32 + rchunk];
#pragma unroll
        for (int n = 0; n < 4; n++)
            bf[n] = *(const f16x8*)&Bs[bsel][(wn + n * 16 + lr) * 32 + rchunk];
#pragma unroll
        for (int m = 0; m < 4; m++)
#pragma unroll
            for (int n = 0; n < 4; n++)
                acc[m][n] = __builtin_amdgcn_mfma_f32_16x16x32_f16(af[m], bf[n], acc[m][n], 0, 0, 0);
        __syncthreads();
        bsel ^= 1;
    }
#undef GSTAGE

#pragma unroll
    for (int m = 0; m < 4; m++)
#pragma unroll
        for (int n = 0; n < 4; n++)
#pragma unroll
            for (int r = 0; r < 4; r++) {
                int row = m0 + wm + m * 16 + lc * 4 + r;
                int col = n0 + wn + n * 16 + lr;
                float v = acc[m][n][r];
                if (bias) v += bias[col] * bscale;
                if (relu) v = fmaxf(v, 0.0f);
                if (Ch) Ch[(size_t)row * N + col] = (f16)v;
                else    Cfb[(size_t)row * N + col] = v * oscale;
            }
}

// ---------------- flash attention (counted-vmcnt pipeline) ----------------
// grid (H, S/64). 4 waves x 16 q-rows. K/V dbuf; raw barriers; loads span iterations.
__global__ __launch_bounds__(256) void k_flash(
    const f16* __restrict__ qkv, const f16* __restrict__ vt, f16* __restrict__ attn) {
    __shared__ f16 Ks[2][4096];
    __shared__ f16 Vs[2][4096];
    __shared__ f16 Ps[4096];
    const int h = blockIdx.x;
    const int qb = blockIdx.y;
    const int t = threadIdx.x, l = t & 63, w = t >> 6;
    const int lr = l & 15, lc = l >> 4;
    const int q0 = qb * 64;
    const int qrow = q0 + w * 16 + lr;

    f16x8 qf0 = *(const f16x8*)&qkv[(size_t)qrow * 3072 + h * 64 + lc * 8];
    f16x8 qf1 = *(const f16x8*)&qkv[(size_t)qrow * 3072 + h * 64 + 32 + lc * 8];

    f32x4 o[4] = {};
    float mrun[4], lrun[4];
#pragma unroll
    for (int r = 0; r < 4; r++) { mrun[r] = -__builtin_inff(); lrun[r] = 0.0f; }

    const int krow = t >> 3;                 // 0..31
    const int kscol = 8 * ((t & 7) ^ (krow & 7));
    const f16* gK = qkv + EE + h * 64;
    const f16* gV = vt + (size_t)(h * 64) * SS;
    f16* Pw = &Ps[w * 16 * 64];
    const int psw = (lr & 7) << 4;

#define FSTAGE(bb, kt_) { \
    char* dK = (char*)Ks[bb] + w * 1024; \
    char* dV = (char*)Vs[bb] + w * 1024; \
    gload16(gK + (size_t)((kt_) * 64 + krow) * 3072 + kscol, dK); \
    gload16(gK + (size_t)((kt_) * 64 + krow + 32) * 3072 + kscol, dK + 4096); \
    gload16(gV + (size_t)krow * SS + (kt_) * 64 + kscol, dV); \
    gload16(gV + (size_t)(krow + 32) * SS + (kt_) * 64 + kscol, dV + 4096); }

    const int nkt = qb + 1;
    FSTAGE(0, 0)
    FSTAGE(1, 1)                              // kt=1 rows exist even when unused (S=2048)
    asm volatile("s_waitcnt vmcnt(4)" ::: "memory");
    __builtin_amdgcn_s_barrier();

    int cur = 0;
    for (int kt = 0; kt < nkt; kt++) {
        // QK^T: scores[16q x 64k] per wave
        f32x4 sc[4];
#pragma unroll
        for (int kj = 0; kj < 4; kj++) {
            const int krw = kj * 16 + lr;
            const int sw = krw & 7;
            f16x8 kb0 = *(const f16x8*)&Ks[cur][krw * 64 + 8 * (lc ^ sw)];
            f16x8 kb1 = *(const f16x8*)&Ks[cur][krw * 64 + 8 * ((lc + 4) ^ sw)];
            f32x4 z = {};
            z = __builtin_amdgcn_mfma_f32_16x16x32_f16(qf0, kb0, z, 0, 0, 0);
            z = __builtin_amdgcn_mfma_f32_16x16x32_f16(qf1, kb1, z, 0, 0, 0);
            sc[kj] = z;
        }

        const bool diag = (kt == qb);
#pragma unroll
        for (int kj = 0; kj < 4; kj++)
#pragma unroll
            for (int r = 0; r < 4; r++) {
                float v = sc[kj][r] * SCORE_SCALE;
                if (diag) {
                    int qq = w * 16 + lc * 4 + r;
                    int kk = kj * 16 + lr;
                    if (kk > qq) v = -__builtin_inff();
                }
                sc[kj][r] = v;
            }

        // online softmax (rows live in 16-lane groups sharing lc)
#pragma unroll
        for (int r = 0; r < 4; r++) {
            float mt = fmaxf(fmaxf(sc[0][r], sc[1][r]), fmaxf(sc[2][r], sc[3][r]));
            mt = fmaxf(mt, __shfl_xor(mt, 1));
            mt = fmaxf(mt, __shfl_xor(mt, 2));
            mt = fmaxf(mt, __shfl_xor(mt, 4));
            mt = fmaxf(mt, __shfl_xor(mt, 8));
            float mnew = fmaxf(mrun[r], mt);
            float alpha = __expf(mrun[r] - mnew);
            float psum = 0.0f;
#pragma unroll
            for (int kj = 0; kj < 4; kj++) {
                float p = __expf(sc[kj][r] - mnew);
                sc[kj][r] = p;
                psum += p;
            }
            psum += __shfl_xor(psum, 1);
            psum += __shfl_xor(psum, 2);
            psum += __shfl_xor(psum, 4);
            psum += __shfl_xor(psum, 8);
            lrun[r] = lrun[r] * alpha + psum;
            mrun[r] = mnew;
#pragma unroll
            for (int dj = 0; dj < 4; dj++) o[dj][r] *= alpha;
        }

        // P -> fp16 -> swizzled LDS (wave-private region; within-wave lgkm ordering only)
#pragma unroll
        for (int kj = 0; kj < 4; kj++)
#pragma unroll
            for (int r = 0; r < 4; r++) {
                int prow = lc * 4 + r;
                int pb = prow * 128 + ((kj * 16 + lr) * 2 ^ ((prow & 7) << 4));
                *(f16*)((char*)Pw + pb) = (f16)sc[kj][r];
            }

        // PV: O[16q x 64d] += P[16q x 64k] * V[64k x 64d]
#pragma unroll
        for (int s2 = 0; s2 < 2; s2++) {
            f16x8 pa = *(const f16x8*)((const char*)Pw + lr * 128 + (((lc + 4 * s2) * 16) ^ psw));
#pragma unroll
            for (int dj = 0; dj < 4; dj++) {
                const int vrow = dj * 16 + lr;
                f16x8 vb = *(const f16x8*)&Vs[cur][vrow * 64 + 8 * ((lc + 4 * s2) ^ (vrow & 7))];
                o[dj] = __builtin_amdgcn_mfma_f32_16x16x32_f16(pa, vb, o[dj], 0, 0, 0);
            }
        }

        asm volatile("" ::: "memory");
        __builtin_amdgcn_s_barrier();         // all waves done with K/V buf[cur]
        if (kt + 2 < nkt) {
            FSTAGE(cur, kt + 2)
            asm volatile("s_waitcnt vmcnt(4)" ::: "memory");   // tile kt+1 landed
        } else if (kt + 1 < nkt) {
            asm volatile("s_waitcnt vmcnt(0)" ::: "memory");
        }
        __builtin_amdgcn_s_barrier();
        cur ^= 1;
    }
#undef FSTAGE

#pragma unroll
    for (int dj = 0; dj < 4; dj++)
#pragma unroll
        for (int r = 0; r < 4; r++) {
            float v = o[dj][r] / lrun[r];
            attn[(size_t)(q0 + w * 16 + lc * 4 + r) * EE + h * 64 + dj * 16 + lr] = (f16)v;
        }
}

// ---------------- host launch ----------------
extern "C" void kernel_launch(void* const* d_in, const int* in_sizes, int n_in,
                              void* d_out, int out_size, void* d_ws, size_t ws_size,
                              hipStream_t stream) {
    const int*   ids  = (const int*)d_in[0];
    const float* emb  = (const float*)d_in[2];
    const float* Wq   = (const float*)d_in[3];
    const float* bq   = (const float*)d_in[4];
    const float* Wk   = (const float*)d_in[5];
    const float* bk   = (const float*)d_in[6];
    const float* Wv   = (const float*)d_in[7];
    const float* bv   = (const float*)d_in[8];
    const float* W1   = (const float*)d_in[9];
    const float* b1   = (const float*)d_in[10];
    const float* W2   = (const float*)d_in[11];
    const float* b2   = (const float*)d_in[12];
    const float* Wout = (const float*)d_in[13];
    float* out = (float*)d_out;

    char* p = (char*)d_ws;
    f16* xh    = (f16*)p; p += (size_t)SS * EE * 2;        // 4 MB
    f16* qkvh  = (f16*)p; p += (size_t)SS * 3 * EE * 2;    // 12 MB
    f16* vt    = (f16*)p; p += (size_t)EE * SS * 2;        // 4 MB
    f16* attn  = (f16*)p; p += (size_t)SS * EE * 2;        // 4 MB
    f16* h1    = (f16*)p; p += (size_t)SS * FF * 2;        // 16 MB
    f16* wqkvt = (f16*)p; p += (size_t)3 * EE * EE * 2;    // 6 MB
    f16* w1t   = (f16*)p; p += (size_t)FF * EE * 2;        // 8 MB
    f16* w2t   = (f16*)p; p += (size_t)EE * FF * 2;        // 8 MB
    f16* woutt = (f16*)p; p += (size_t)NV * EE * 2;        // 64 MB
    float* part = (float*)p; p += (size_t)2 * SS * EE * 4; // 16 MB
    float* bqkv = (float*)p; p += 3 * EE * 4;

    dim3 b32(32, 32);

    k_embed<<<SS, 256, 0, stream>>>(ids, emb, xh);

    for (int l = 0; l < NL; l++) {
        k_transpose_fused<<<11264, b32, 0, stream>>>(
            Wq + (size_t)l * EE * EE, Wk + (size_t)l * EE * EE, Wv + (size_t)l * EE * EE,
            W1 + (size_t)l * EE * FF, W2 + (size_t)l * FF * EE, wqkvt, w1t, w2t);
        k_concat3<<<12, 256, 0, stream>>>(bq + l * EE, bk + l * EE, bv + l * EE, bqkv);

        // QKV: [2048,1024] x [3072,1024]^T -> qkvh. BM=256,BN=128 grid 8*24=192
        k_gemm256<128><<<8 * 24, 512, 0, stream>>>(
            xh, wqkvt, bqkv, qkvh, nullptr, SS, 3 * EE, EE, EE, 8, 24, 1, CS, 1.0f, 0);

        k_transpose_h<<<dim3(EE / 32, SS / 32), b32, 0, stream>>>(qkvh + 2 * EE, vt, 3 * EE, SS);

        k_flash<<<dim3(NH, SS / 64), 256, 0, stream>>>(qkvh, vt, attn);

        // FFN1 + relu: [2048,1024] x [4096,1024]^T -> h1. grid 8*32=256
        k_gemm256<128><<<8 * 32, 512, 0, stream>>>(
            attn, w1t, b1 + (size_t)l * FF, h1, nullptr, SS, FF, EE, EE, 8, 32, 1, CS, 1.0f, 1);

        // FFN2 split-K=2 on 128^2 kernel: grid 16*8*2
        k_gemm_bt<<<16 * 8 * 2, 256, 0, stream>>>(
            h1, w2t, nullptr, nullptr, part, SS, EE, FF, FF / 2, 16, 8, 2, 0.0f, 1.0f, 0);
        k_combine2<<<SS * EE / 1024, 256, 0, stream>>>(
            part, part + (size_t)SS * EE, b2 + (size_t)l * EE, xh);
    }

    // logits: [2048,1024] x [32000,1024]^T -> fp32 out. BN=256 grid 8*125=1000
    k_transpose_f32_f16<<<dim3(NV / 32, EE / 32), b32, 0, stream>>>(Wout, woutt, NV, EE);
    k_gemm256<256><<<8 * 125, 512, 0, stream>>>(
        xh, woutt, nullptr, nullptr, out, SS, NV, EE, EE, 8, 125, 1, 0.0f, INV_CS, 0);
}

// Round 4
// 1824.617 us; speedup vs baseline: 1.3276x; 1.0176x over previous
//
#include <hip/hip_runtime.h>
#include <hip/hip_fp16.h>

// StackedAttentionModel: 8-layer transformer fwd, S=2048 E=1024 H=16 D=64 F=4096 V=32000.
// fp16 MFMA (fp32 accum), global activation scale CS=2^12 folded out exactly.
// R4: m201-style phase-split K-loop (ds_read burst -> barrier -> setprio+MFMA -> barrier),
//     tile-boundary counted vmcnt kept from R3; FFN2 on gemm256 split-K=4; setprio in flash.

#define SS 2048
#define EE 1024
#define NH 16
#define FF 4096
#define NV 32000
#define NL 8

typedef _Float16 f16;
typedef _Float16 f16x8 __attribute__((ext_vector_type(8)));
typedef _Float16 f16x4 __attribute__((ext_vector_type(4)));
typedef float f32x4 __attribute__((ext_vector_type(4)));

#define CS 4096.0f          // 2^12 activation scale
#define INV_CS 0.000244140625f
#define SCORE_SCALE 7.450580596923828e-09f  // 1/(8*CS^2) = 2^-27

__device__ __forceinline__ void gload16(const void* g, void* lds) {
    __builtin_amdgcn_global_load_lds(
        (const __attribute__((address_space(1))) unsigned int*)g,
        (__attribute__((address_space(3))) unsigned int*)lds, 16, 0, 0);
}

// ---------------- embedding gather (fp32 -> fp16 * CS) ----------------
__global__ void k_embed(const int* __restrict__ ids, const float* __restrict__ emb,
                        f16* __restrict__ xh) {
    int s = blockIdx.x;
    int e = threadIdx.x * 4;
    const float4 v = *(const float4*)&emb[(size_t)ids[s] * EE + e];
    f16x4 h;
    h[0] = (f16)(v.x * CS); h[1] = (f16)(v.y * CS);
    h[2] = (f16)(v.z * CS); h[3] = (f16)(v.w * CS);
    *(f16x4*)&xh[(size_t)s * EE + e] = h;
}

// ---------------- single transpose fp32 -> fp16 (Wout) ----------------
__global__ void k_transpose_f32_f16(const float* __restrict__ in, f16* __restrict__ out,
                                    int ldi, int ldo) {
    __shared__ float tile[32][33];
    int bx = blockIdx.x * 32, by = blockIdx.y * 32;
    int tx = threadIdx.x, ty = threadIdx.y;
    tile[ty][tx] = in[(size_t)(by + ty) * ldi + bx + tx];
    __syncthreads();
    out[(size_t)(bx + ty) * ldo + by + tx] = (f16)tile[tx][ty];
}

// fused per-layer weight transposes: Wq,Wk,Wv, W1, W2
__global__ void k_transpose_fused(const float* __restrict__ Wq, const float* __restrict__ Wk,
                                  const float* __restrict__ Wv, const float* __restrict__ W1,
                                  const float* __restrict__ W2,
                                  f16* __restrict__ wqkvt, f16* __restrict__ w1t,
                                  f16* __restrict__ w2t) {
    __shared__ float tile[32][33];
    int b = blockIdx.x;
    const float* in; f16* out; int ldi, ldo, bx, by;
    if (b < 3072) {
        int s = b >> 10, t2 = b & 1023;
        in = s == 0 ? Wq : (s == 1 ? Wk : Wv);
        out = wqkvt + (size_t)s * EE * EE; ldi = EE; ldo = EE;
        bx = (t2 & 31) * 32; by = (t2 >> 5) * 32;
    } else if (b < 7168) {
        int t2 = b - 3072;
        in = W1; out = w1t; ldi = FF; ldo = EE;
        bx = (t2 & 127) * 32; by = (t2 >> 7) * 32;
    } else {
        int t2 = b - 7168;
        in = W2; out = w2t; ldi = EE; ldo = FF;
        bx = (t2 & 31) * 32; by = (t2 >> 5) * 32;
    }
    int tx = threadIdx.x, ty = threadIdx.y;
    tile[ty][tx] = in[(size_t)(by + ty) * ldi + bx + tx];
    __syncthreads();
    out[(size_t)(bx + ty) * ldo + by + tx] = (f16)tile[tx][ty];
}

// fp16 -> fp16 transpose (V -> V^T)
__global__ void k_transpose_h(const f16* __restrict__ in, f16* __restrict__ out,
                              int ldi, int ldo) {
    __shared__ f16 tile[32][33];
    int bx = blockIdx.x * 32, by = blockIdx.y * 32;
    int tx = threadIdx.x, ty = threadIdx.y;
    tile[ty][tx] = in[(size_t)(by + ty) * ldi + bx + tx];
    __syncthreads();
    out[(size_t)(bx + ty) * ldo + by + tx] = tile[tx][ty];
}

__global__ void k_concat3(const float* __restrict__ a, const float* __restrict__ b,
                          const float* __restrict__ c, float* __restrict__ o) {
    int i = blockIdx.x * 256 + threadIdx.x;
    o[i] = i < EE ? a[i] : (i < 2 * EE ? b[i - EE] : c[i - 2 * EE]);
}

// split-K=4 combiner: out = f16(p0+p1+p2+p3 + bias*CS)
__global__ void k_combine4(const float* __restrict__ part, const float* __restrict__ bias,
                           f16* __restrict__ out) {
    const size_t sz = (size_t)SS * EE;
    int i = (blockIdx.x * 256 + threadIdx.x) * 4;
    float4 a = *(const float4*)&part[i];
    float4 b = *(const float4*)&part[i + sz];
    float4 c = *(const float4*)&part[i + 2 * sz];
    float4 d = *(const float4*)&part[i + 3 * sz];
    float4 bb = *(const float4*)&bias[i & (EE - 1)];
    f16x4 h;
    h[0] = (f16)(a.x + b.x + c.x + d.x + bb.x * CS);
    h[1] = (f16)(a.y + b.y + c.y + d.y + bb.y * CS);
    h[2] = (f16)(a.z + b.z + c.z + d.z + bb.z * CS);
    h[3] = (f16)(a.w + b.w + c.w + d.w + bb.w * CS);
    *(f16x4*)&out[i] = h;
}

// ================= 256-row GEMM, phase-split + counted-vmcnt =================
// C[M,N] = A[M,K] * B[N,K]^T. BM=256, BK=64, 8 waves.
// BN=256: waves 2x4, wave tile 128x64 (MR=8) -> 4 phases/K-tile of 16 MFMA.
// BN=128: waves 4x2, wave tile 64x64 (MR=4)  -> 2 phases/K-tile of 16 MFMA.
// Each phase: {ds_read 4-8 x b128; barrier; setprio(1); 16 MFMA; setprio(0); barrier}.
// Tile boundary: STAGE(tt+2) -> vmcnt(LPT) (tile tt+1 landed, tt+2 in flight) -> barrier.
template<int BN>
__global__ __launch_bounds__(512, 2) void k_gemm256(
    const f16* __restrict__ A, const f16* __restrict__ B,
    const float* __restrict__ bias, f16* __restrict__ Ch, float* __restrict__ Cf,
    int M, int N, int Kstride, int Ksub, int nm, int nn, int kch,
    float bscale, float oscale, int relu) {
    constexpr int WN = (BN == 256) ? 4 : 2;
    constexpr int MR = (BN == 256) ? 8 : 4;     // wave tile rows / 16
    constexpr int BCALLS = BN / 64;             // B stage calls per tile
    constexpr int LPT = 4 + BCALLS;             // loads/tile per wave

    __shared__ f16 As[2][256 * 64];
    __shared__ f16 Bs[2][BN * 64];

    const int t = threadIdx.x;
    const int l = t & 63, w = t >> 6;
    const int lr = l & 15, lc = l >> 4;

    const int nwg = nm * nn * kch;
    const int q8 = nwg >> 3, r8 = nwg & 7;
    const int xcd = blockIdx.x & 7, lid = blockIdx.x >> 3;
    const int wgid = (xcd < r8 ? xcd * (q8 + 1) : r8 * (q8 + 1) + (xcd - r8) * q8) + lid;
    const int kc = wgid / (nm * nn);
    const int rem = wgid - kc * (nm * nn);
    const int m0 = (rem % nm) * 256, n0 = (rem / nm) * BN;

    const f16* Ab = A + (size_t)kc * Ksub;
    const f16* Bb = B + (size_t)kc * Ksub;
    float* Cfb = Cf ? Cf + (size_t)kc * M * N : nullptr;

    const int wr = w / WN, wc = w % WN;

    f32x4 acc[MR][4] = {};

    // staging coords: call c covers rows c*64 + (t>>3); source col-chunk XOR-swizzled
    const int srow = t >> 3;
    const int scol = 8 * ((t & 7) ^ (srow & 7));
    const int NT = Ksub / 64;

#define STAGE(bb, tt_) { \
    const size_t kof = (size_t)(tt_) * 64 + scol; \
    _Pragma("unroll") \
    for (int c = 0; c < 4; c++) \
        gload16(Ab + (size_t)(m0 + c * 64 + srow) * Kstride + kof, \
                (char*)As[bb] + c * 8192 + w * 1024); \
    _Pragma("unroll") \
    for (int c = 0; c < BCALLS; c++) \
        gload16(Bb + (size_t)(n0 + c * 64 + srow) * Kstride + kof, \
                (char*)Bs[bb] + c * 8192 + w * 1024); }

    STAGE(0, 0)
    STAGE(1, 1)
    asm volatile("s_waitcnt vmcnt(%0)" :: "n"(LPT) : "memory");
    __builtin_amdgcn_s_barrier();

    int cur = 0;
    for (int tt = 0; tt < NT; ++tt) {
        const f16* pA = As[cur];
        const f16* pB = Bs[cur];
#pragma unroll
        for (int ks = 0; ks < 2; ks++) {
            f16x8 bf[4];
#pragma unroll
            for (int n = 0; n < 4; n++) {
                const int row = wc * 64 + n * 16 + lr;
                bf[n] = *(const f16x8*)&pB[row * 64 + 8 * ((ks * 4 + lc) ^ (row & 7))];
            }
#pragma unroll
            for (int mh = 0; mh < MR / 4; mh++) {
                f16x8 af[4];
#pragma unroll
                for (int m = 0; m < 4; m++) {
                    const int row = wr * (MR * 16) + (mh * 4 + m) * 16 + lr;
                    af[m] = *(const f16x8*)&pA[row * 64 + 8 * ((ks * 4 + lc) ^ (row & 7))];
                }
                asm volatile("" ::: "memory");
                __builtin_amdgcn_s_barrier();       // reads issued; settle during wait
                __builtin_amdgcn_s_setprio(1);
#pragma unroll
                for (int m = 0; m < 4; m++)
#pragma unroll
                    for (int n = 0; n < 4; n++)
                        acc[mh * 4 + m][n] = __builtin_amdgcn_mfma_f32_16x16x32_f16(
                            af[m], bf[n], acc[mh * 4 + m][n], 0, 0, 0);
                __builtin_amdgcn_s_setprio(0);
                asm volatile("" ::: "memory");
                __builtin_amdgcn_s_barrier();       // phase end
            }
        }
        // tile boundary: buf[cur] fully consumed by all waves (last phase barrier)
        if (tt + 2 < NT) {
            STAGE(cur, tt + 2)
            asm volatile("s_waitcnt vmcnt(%0)" :: "n"(LPT) : "memory");  // tile tt+1 landed
        } else if (tt + 1 < NT) {
            asm volatile("s_waitcnt vmcnt(0)" ::: "memory");
        }
        __builtin_amdgcn_s_barrier();
        cur ^= 1;
    }
#undef STAGE

#pragma unroll
    for (int m = 0; m < MR; m++)
#pragma unroll
        for (int n = 0; n < 4; n++)
#pragma unroll
            for (int r = 0; r < 4; r++) {
                int row = m0 + wr * (MR * 16) + m * 16 + lc * 4 + r;
                int col = n0 + wc * 64 + n * 16 + lr;
                float v = acc[m][n][r];
                if (bias) v += bias[col] * bscale;
                if (relu) v = fmaxf(v, 0.0f);
                if (Ch) Ch[(size_t)row * N + col] = (f16)v;
                else    Cfb[(size_t)row * N + col] = v * oscale;
            }
}

// ---------------- flash attention (counted-vmcnt pipeline, R3 structure + setprio) ----------------
__global__ __launch_bounds__(256) void k_flash(
    const f16* __restrict__ qkv, const f16* __restrict__ vt, f16* __restrict__ attn) {
    __shared__ f16 Ks[2][4096];
    __shared__ f16 Vs[2][4096];
    __shared__ f16 Ps[4096];
    const int h = blockIdx.x;
    const int qb = blockIdx.y;
    const int t = threadIdx.x, l = t & 63, w = t >> 6;
    const int lr = l & 15, lc = l >> 4;
    const int q0 = qb * 64;
    const int qrow = q0 + w * 16 + lr;

    f16x8 qf0 = *(const f16x8*)&qkv[(size_t)qrow * 3072 + h * 64 + lc * 8];
    f16x8 qf1 = *(const f16x8*)&qkv[(size_t)qrow * 3072 + h * 64 + 32 + lc * 8];

    f32x4 o[4] = {};
    float mrun[4], lrun[4];
#pragma unroll
    for (int r = 0; r < 4; r++) { mrun[r] = -__builtin_inff(); lrun[r] = 0.0f; }

    const int krow = t >> 3;                 // 0..31
    const int kscol = 8 * ((t & 7) ^ (krow & 7));
    const f16* gK = qkv + EE + h * 64;
    const f16* gV = vt + (size_t)(h * 64) * SS;
    f16* Pw = &Ps[w * 16 * 64];
    const int psw = (lr & 7) << 4;

#define FSTAGE(bb, kt_) { \
    char* dK = (char*)Ks[bb] + w * 1024; \
    char* dV = (char*)Vs[bb] + w * 1024; \
    gload16(gK + (size_t)((kt_) * 64 + krow) * 3072 + kscol, dK); \
    gload16(gK + (size_t)((kt_) * 64 + krow + 32) * 3072 + kscol, dK + 4096); \
    gload16(gV + (size_t)krow * SS + (kt_) * 64 + kscol, dV); \
    gload16(gV + (size_t)(krow + 32) * SS + (kt_) * 64 + kscol, dV + 4096); }

    const int nkt = qb + 1;
    FSTAGE(0, 0)
    FSTAGE(1, 1)                              // kt=1 rows exist even when unused (S=2048)
    asm volatile("s_waitcnt vmcnt(4)" ::: "memory");
    __builtin_amdgcn_s_barrier();

    int cur = 0;
    for (int kt = 0; kt < nkt; kt++) {
        // QK^T: scores[16q x 64k] per wave
        f32x4 sc[4];
        __builtin_amdgcn_s_setprio(1);
#pragma unroll
        for (int kj = 0; kj < 4; kj++) {
            const int krw = kj * 16 + lr;
            const int sw = krw & 7;
            f16x8 kb0 = *(const f16x8*)&Ks[cur][krw * 64 + 8 * (lc ^ sw)];
            f16x8 kb1 = *(const f16x8*)&Ks[cur][krw * 64 + 8 * ((lc + 4) ^ sw)];
            f32x4 z = {};
            z = __builtin_amdgcn_mfma_f32_16x16x32_f16(qf0, kb0, z, 0, 0, 0);
            z = __builtin_amdgcn_mfma_f32_16x16x32_f16(qf1, kb1, z, 0, 0, 0);
            sc[kj] = z;
        }
        __builtin_amdgcn_s_setprio(0);

        const bool diag = (kt == qb);
#pragma unroll
        for (int kj = 0; kj < 4; kj++)
#pragma unroll
            for (int r = 0; r < 4; r++) {
                float v = sc[kj][r] * SCORE_SCALE;
                if (diag) {
                    int qq = w * 16 + lc * 4 + r;
                    int kk = kj * 16 + lr;
                    if (kk > qq) v = -__builtin_inff();
                }
                sc[kj][r] = v;
            }

        // online softmax (rows live in 16-lane groups sharing lc)
#pragma unroll
        for (int r = 0; r < 4; r++) {
            float mt = fmaxf(fmaxf(sc[0][r], sc[1][r]), fmaxf(sc[2][r], sc[3][r]));
            mt = fmaxf(mt, __shfl_xor(mt, 1));
            mt = fmaxf(mt, __shfl_xor(mt, 2));
            mt = fmaxf(mt, __shfl_xor(mt, 4));
            mt = fmaxf(mt, __shfl_xor(mt, 8));
            float mnew = fmaxf(mrun[r], mt);
            float alpha = __expf(mrun[r] - mnew);
            float psum = 0.0f;
#pragma unroll
            for (int kj = 0; kj < 4; kj++) {
                float p = __expf(sc[kj][r] - mnew);
                sc[kj][r] = p;
                psum += p;
            }
            psum += __shfl_xor(psum, 1);
            psum += __shfl_xor(psum, 2);
            psum += __shfl_xor(psum, 4);
            psum += __shfl_xor(psum, 8);
            lrun[r] = lrun[r] * alpha + psum;
            mrun[r] = mnew;
#pragma unroll
            for (int dj = 0; dj < 4; dj++) o[dj][r] *= alpha;
        }

        // P -> fp16 -> swizzled LDS (wave-private region)
#pragma unroll
        for (int kj = 0; kj < 4; kj++)
#pragma unroll
            for (int r = 0; r < 4; r++) {
                int prow = lc * 4 + r;
                int pb = prow * 128 + ((kj * 16 + lr) * 2 ^ ((prow & 7) << 4));
                *(f16*)((char*)Pw + pb) = (f16)sc[kj][r];
            }

        // PV: O[16q x 64d] += P[16q x 64k] * V[64k x 64d]
        __builtin_amdgcn_s_setprio(1);
#pragma unroll
        for (int s2 = 0; s2 < 2; s2++) {
            f16x8 pa = *(const f16x8*)((const char*)Pw + lr * 128 + (((lc + 4 * s2) * 16) ^ psw));
#pragma unroll
            for (int dj = 0; dj < 4; dj++) {
                const int vrow = dj * 16 + lr;
                f16x8 vb = *(const f16x8*)&Vs[cur][vrow * 64 + 8 * ((lc + 4 * s2) ^ (vrow & 7))];
                o[dj] = __builtin_amdgcn_mfma_f32_16x16x32_f16(pa, vb, o[dj], 0, 0, 0);
            }
        }
        __builtin_amdgcn_s_setprio(0);

        asm volatile("" ::: "memory");
        __builtin_amdgcn_s_barrier();         // all waves done with K/V buf[cur]
        if (kt + 2 < nkt) {
            FSTAGE(cur, kt + 2)
            asm volatile("s_waitcnt vmcnt(4)" ::: "memory");   // tile kt+1 landed
        } else if (kt + 1 < nkt) {
            asm volatile("s_waitcnt vmcnt(0)" ::: "memory");
        }
        __builtin_amdgcn_s_barrier();
        cur ^= 1;
    }
#undef FSTAGE

#pragma unroll
    for (int dj = 0; dj < 4; dj++)
#pragma unroll
        for (int r = 0; r < 4; r++) {
            float v = o[dj][r] / lrun[r];
            attn[(size_t)(q0 + w * 16 + lc * 4 + r) * EE + h * 64 + dj * 16 + lr] = (f16)v;
        }
}

// ---------------- host launch ----------------
extern "C" void kernel_launch(void* const* d_in, const int* in_sizes, int n_in,
                              void* d_out, int out_size, void* d_ws, size_t ws_size,
                              hipStream_t stream) {
    const int*   ids  = (const int*)d_in[0];
    const float* emb  = (const float*)d_in[2];
    const float* Wq   = (const float*)d_in[3];
    const float* bq   = (const float*)d_in[4];
    const float* Wk   = (const float*)d_in[5];
    const float* bk   = (const float*)d_in[6];
    const float* Wv   = (const float*)d_in[7];
    const float* bv   = (const float*)d_in[8];
    const float* W1   = (const float*)d_in[9];
    const float* b1   = (const float*)d_in[10];
    const float* W2   = (const float*)d_in[11];
    const float* b2   = (const float*)d_in[12];
    const float* Wout = (const float*)d_in[13];
    float* out = (float*)d_out;

    char* p = (char*)d_ws;
    f16* xh    = (f16*)p; p += (size_t)SS * EE * 2;        // 4 MB
    f16* qkvh  = (f16*)p; p += (size_t)SS * 3 * EE * 2;    // 12 MB
    f16* vt    = (f16*)p; p += (size_t)EE * SS * 2;        // 4 MB
    f16* attn  = (f16*)p; p += (size_t)SS * EE * 2;        // 4 MB
    f16* h1    = (f16*)p; p += (size_t)SS * FF * 2;        // 16 MB
    f16* wqkvt = (f16*)p; p += (size_t)3 * EE * EE * 2;    // 6 MB
    f16* w1t   = (f16*)p; p += (size_t)FF * EE * 2;        // 8 MB
    f16* w2t   = (f16*)p; p += (size_t)EE * FF * 2;        // 8 MB
    f16* woutt = (f16*)p; p += (size_t)NV * EE * 2;        // 64 MB
    float* part = (float*)p; p += (size_t)4 * SS * EE * 4; // 32 MB (split-K=4 partials)
    float* bqkv = (float*)p; p += 3 * EE * 4;

    dim3 b32(32, 32);

    k_embed<<<SS, 256, 0, stream>>>(ids, emb, xh);

    for (int l = 0; l < NL; l++) {
        k_transpose_fused<<<11264, b32, 0, stream>>>(
            Wq + (size_t)l * EE * EE, Wk + (size_t)l * EE * EE, Wv + (size_t)l * EE * EE,
            W1 + (size_t)l * EE * FF, W2 + (size_t)l * FF * EE, wqkvt, w1t, w2t);
        k_concat3<<<12, 256, 0, stream>>>(bq + l * EE, bk + l * EE, bv + l * EE, bqkv);

        // QKV: [2048,1024] x [3072,1024]^T -> qkvh. BM=256,BN=128 grid 8*24=192
        k_gemm256<128><<<8 * 24, 512, 0, stream>>>(
            xh, wqkvt, bqkv, qkvh, nullptr, SS, 3 * EE, EE, EE, 8, 24, 1, CS, 1.0f, 0);

        k_transpose_h<<<dim3(EE / 32, SS / 32), b32, 0, stream>>>(qkvh + 2 * EE, vt, 3 * EE, SS);

        k_flash<<<dim3(NH, SS / 64), 256, 0, stream>>>(qkvh, vt, attn);

        // FFN1 + relu: [2048,1024] x [4096,1024]^T -> h1. grid 8*32=256
        k_gemm256<128><<<8 * 32, 512, 0, stream>>>(
            attn, w1t, b1 + (size_t)l * FF, h1, nullptr, SS, FF, EE, EE, 8, 32, 1, CS, 1.0f, 1);

        // FFN2 split-K=4: [2048,4096] x [1024,4096]^T -> fp32 partials. grid 8*8*4=256
        k_gemm256<128><<<8 * 8 * 4, 512, 0, stream>>>(
            h1, w2t, nullptr, nullptr, part, SS, EE, FF, FF / 4, 8, 8, 4, 0.0f, 1.0f, 0);
        k_combine4<<<SS * EE / 1024, 256, 0, stream>>>(part, b2 + (size_t)l * EE, xh);
    }

    // logits: [2048,1024] x [32000,1024]^T -> fp32 out. BN=256 grid 8*125=1000
    k_transpose_f32_f16<<<dim3(NV / 32, EE / 32), b32, 0, stream>>>(Wout, woutt, NV, EE);
    k_gemm256<256><<<8 * 125, 512, 0, stream>>>(
        xh, woutt, nullptr, nullptr, out, SS, NV, EE, EE, 8, 125, 1, 0.0f, INV_CS, 0);
}

// Round 5
// 1763.257 us; speedup vs baseline: 1.3738x; 1.0348x over previous
//
#include <hip/hip_runtime.h>
#include <hip/hip_fp16.h>

// StackedAttentionModel: 8-layer transformer fwd, S=2048 E=1024 H=16 D=64 F=4096 V=32000.
// fp16 MFMA (fp32 accum), global activation scale CS=2^12 folded out exactly.
// R5: register-skewed phase pipeline (ds_read for subtile p+1 overlaps MFMA of subtile p),
//     V-transpose fused into QKV epilogue, bias-concat folded into weight-transpose kernel.

#define SS 2048
#define EE 1024
#define NH 16
#define FF 4096
#define NV 32000
#define NL 8

typedef _Float16 f16;
typedef _Float16 f16x8 __attribute__((ext_vector_type(8)));
typedef _Float16 f16x4 __attribute__((ext_vector_type(4)));
typedef float f32x4 __attribute__((ext_vector_type(4)));

#define CS 4096.0f          // 2^12 activation scale
#define INV_CS 0.000244140625f
#define SCORE_SCALE 7.450580596923828e-09f  // 1/(8*CS^2) = 2^-27

__device__ __forceinline__ void gload16(const void* g, void* lds) {
    __builtin_amdgcn_global_load_lds(
        (const __attribute__((address_space(1))) unsigned int*)g,
        (__attribute__((address_space(3))) unsigned int*)lds, 16, 0, 0);
}

#define BAR do { asm volatile("" ::: "memory"); __builtin_amdgcn_s_barrier(); } while (0)

// ---------------- embedding gather (fp32 -> fp16 * CS) ----------------
__global__ void k_embed(const int* __restrict__ ids, const float* __restrict__ emb,
                        f16* __restrict__ xh) {
    int s = blockIdx.x;
    int e = threadIdx.x * 4;
    const float4 v = *(const float4*)&emb[(size_t)ids[s] * EE + e];
    f16x4 h;
    h[0] = (f16)(v.x * CS); h[1] = (f16)(v.y * CS);
    h[2] = (f16)(v.z * CS); h[3] = (f16)(v.w * CS);
    *(f16x4*)&xh[(size_t)s * EE + e] = h;
}

// ---------------- single transpose fp32 -> fp16 (Wout) ----------------
__global__ void k_transpose_f32_f16(const float* __restrict__ in, f16* __restrict__ out,
                                    int ldi, int ldo) {
    __shared__ float tile[32][33];
    int bx = blockIdx.x * 32, by = blockIdx.y * 32;
    int tx = threadIdx.x, ty = threadIdx.y;
    tile[ty][tx] = in[(size_t)(by + ty) * ldi + bx + tx];
    __syncthreads();
    out[(size_t)(bx + ty) * ldo + by + tx] = (f16)tile[tx][ty];
}

// fused per-layer weight transposes + bias concat
__global__ void k_transpose_fused(const float* __restrict__ Wq, const float* __restrict__ Wk,
                                  const float* __restrict__ Wv, const float* __restrict__ W1,
                                  const float* __restrict__ W2,
                                  const float* __restrict__ bq, const float* __restrict__ bk,
                                  const float* __restrict__ bv,
                                  f16* __restrict__ wqkvt, f16* __restrict__ w1t,
                                  f16* __restrict__ w2t, float* __restrict__ bqkv) {
    int b = blockIdx.x;
    int tx = threadIdx.x, ty = threadIdx.y;
    if (b == 11264) {            // bias concat: 3072 floats, 1024 threads
        int i = ty * 32 + tx;
#pragma unroll
        for (int j = 0; j < 3; j++) {
            int idx = j * 1024 + i;
            bqkv[idx] = idx < EE ? bq[idx] : (idx < 2 * EE ? bk[idx - EE] : bv[idx - 2 * EE]);
        }
        return;
    }
    __shared__ float tile[32][33];
    const float* in; f16* out; int ldi, ldo, bx, by;
    if (b < 3072) {
        int s = b >> 10, t2 = b & 1023;
        in = s == 0 ? Wq : (s == 1 ? Wk : Wv);
        out = wqkvt + (size_t)s * EE * EE; ldi = EE; ldo = EE;
        bx = (t2 & 31) * 32; by = (t2 >> 5) * 32;
    } else if (b < 7168) {
        int t2 = b - 3072;
        in = W1; out = w1t; ldi = FF; ldo = EE;
        bx = (t2 & 127) * 32; by = (t2 >> 7) * 32;
    } else {
        int t2 = b - 7168;
        in = W2; out = w2t; ldi = EE; ldo = FF;
        bx = (t2 & 31) * 32; by = (t2 >> 5) * 32;
    }
    tile[ty][tx] = in[(size_t)(by + ty) * ldi + bx + tx];
    __syncthreads();
    out[(size_t)(bx + ty) * ldo + by + tx] = (f16)tile[tx][ty];
}

// split-K=4 combiner: out = f16(p0+p1+p2+p3 + bias*CS)
__global__ void k_combine4(const float* __restrict__ part, const float* __restrict__ bias,
                           f16* __restrict__ out) {
    const size_t sz = (size_t)SS * EE;
    int i = (blockIdx.x * 256 + threadIdx.x) * 4;
    float4 a = *(const float4*)&part[i];
    float4 b = *(const float4*)&part[i + sz];
    float4 c = *(const float4*)&part[i + 2 * sz];
    float4 d = *(const float4*)&part[i + 3 * sz];
    float4 bb = *(const float4*)&bias[i & (EE - 1)];
    f16x4 h;
    h[0] = (f16)(a.x + b.x + c.x + d.x + bb.x * CS);
    h[1] = (f16)(a.y + b.y + c.y + d.y + bb.y * CS);
    h[2] = (f16)(a.z + b.z + c.z + d.z + bb.z * CS);
    h[3] = (f16)(a.w + b.w + c.w + d.w + bb.w * CS);
    *(f16x4*)&out[i] = h;
}

// ================= 256-row GEMM, register-skewed phase pipeline =================
// C[M,N] = A[M,K] * B[N,K]^T. BM=256, BK=64, 8 waves, 128KB LDS dbuf.
// BN=256: waves 2x4, wave tile 128x64 (MR=8), 4 phases of 16 MFMA per K-tile.
// BN=128: waves 4x2, wave tile 64x64 (MR=4), 2 phases of 16 MFMA per K-tile.
// Phase p: {issue ds_reads for subtile p+1} BAR {setprio 16xMFMA on subtile p regs} BAR.
// Reads always one phase ahead -> LDS pipe overlaps MFMA pipe across waves.
// Boundary (STAGE tile tt+2, vmcnt(LPT) = tile tt+1 landed) sits between last two phases,
// so the next tile's first reads (from buf cur^1, landed) overlap the last MFMA cluster.
template<int BN>
__global__ __launch_bounds__(512, 2) void k_gemm256(
    const f16* __restrict__ A, const f16* __restrict__ B,
    const float* __restrict__ bias, f16* __restrict__ Ch, float* __restrict__ Cf,
    f16* __restrict__ VtOut,
    int M, int N, int Kstride, int Ksub, int nm, int nn, int kch,
    float bscale, float oscale, int relu) {
    constexpr int WN = (BN == 256) ? 4 : 2;
    constexpr int MR = (BN == 256) ? 8 : 4;
    constexpr int BCALLS = BN / 64;
    constexpr int LPT = 4 + BCALLS;

    __shared__ f16 As[2][256 * 64];
    __shared__ f16 Bs[2][BN * 64];

    const int t = threadIdx.x;
    const int l = t & 63, w = t >> 6;
    const int lr = l & 15, lc = l >> 4;

    const int nwg = nm * nn * kch;
    const int q8 = nwg >> 3, r8 = nwg & 7;
    const int xcd = blockIdx.x & 7, lid = blockIdx.x >> 3;
    const int wgid = (xcd < r8 ? xcd * (q8 + 1) : r8 * (q8 + 1) + (xcd - r8) * q8) + lid;
    const int kc = wgid / (nm * nn);
    const int rem = wgid - kc * (nm * nn);
    const int m0 = (rem % nm) * 256, n0 = (rem / nm) * BN;

    const f16* Ab = A + (size_t)kc * Ksub;
    const f16* Bb = B + (size_t)kc * Ksub;
    float* Cfb = Cf ? Cf + (size_t)kc * M * N : nullptr;

    const int wr = w / WN, wc = w % WN;

    f32x4 acc[MR][4] = {};
    f16x8 afA[4], afB[4], bf0[4], bf1[4];

    const int srow = t >> 3;
    const int scol = 8 * ((t & 7) ^ (srow & 7));
    const int NT = Ksub / 64;

#define STAGE(bb, tt_) { \
    const size_t kof = (size_t)(tt_) * 64 + scol; \
    _Pragma("unroll") \
    for (int c = 0; c < 4; c++) \
        gload16(Ab + (size_t)(m0 + c * 64 + srow) * Kstride + kof, \
                (char*)As[bb] + c * 8192 + w * 1024); \
    _Pragma("unroll") \
    for (int c = 0; c < BCALLS; c++) \
        gload16(Bb + (size_t)(n0 + c * 64 + srow) * Kstride + kof, \
                (char*)Bs[bb] + c * 8192 + w * 1024); }

#define LDA(dst, pA_, ks, mh) { _Pragma("unroll") \
    for (int m = 0; m < 4; m++) { \
        const int row = wr * (MR * 16) + ((mh) * 4 + m) * 16 + lr; \
        dst[m] = *(const f16x8*)&pA_[row * 64 + 8 * (((ks) * 4 + lc) ^ (row & 7))]; } }

#define LDB(dst, pB_, ks) { _Pragma("unroll") \
    for (int n = 0; n < 4; n++) { \
        const int row = wc * 64 + n * 16 + lr; \
        dst[n] = *(const f16x8*)&pB_[row * 64 + 8 * (((ks) * 4 + lc) ^ (row & 7))]; } }

#define MMA(lo, af_, bf_) { __builtin_amdgcn_s_setprio(1); \
    _Pragma("unroll") for (int m = 0; m < 4; m++) \
    _Pragma("unroll") for (int n = 0; n < 4; n++) \
        acc[(lo) + m][n] = __builtin_amdgcn_mfma_f32_16x16x32_f16(af_[m], bf_[n], acc[(lo) + m][n], 0, 0, 0); \
    __builtin_amdgcn_s_setprio(0); }

    STAGE(0, 0)
    STAGE(1, 1)
    asm volatile("s_waitcnt vmcnt(%0)" :: "n"(LPT) : "memory");
    BAR;
    {   // prologue: regs for subtile 0 of tile 0
        const f16* pA = As[0]; const f16* pB = Bs[0];
        LDA(afA, pA, 0, 0)
        LDB(bf0, pB, 0)
    }

    int cur = 0;
    for (int tt = 0; tt < NT; ++tt) {
        const f16* pA = As[cur];
        const f16* pB = Bs[cur];
        const f16* pAn = As[cur ^ 1];
        const f16* pBn = Bs[cur ^ 1];

        // phase 0: prefetch subtile (ks1,mh0); compute (ks0,mh0)
        LDA(afB, pA, 1, 0)
        LDB(bf1, pB, 1)
        BAR;
        MMA(0, afA, bf0)
        BAR;

        if (BN == 256) {
            // phase 1: prefetch (ks0,mh1); compute (ks1,mh0)
            LDA(afA, pA, 0, 1)
            BAR;
            MMA(0, afB, bf1)
            BAR;
            // phase 2: prefetch (ks1,mh1); compute (ks0,mh1)
            LDA(afB, pA, 1, 1)
            BAR;
            MMA(4, afA, bf0)
            BAR;
        }

        // boundary: buf[cur] reads all issued; stage tile tt+2 into it.
        if (tt + 2 < NT) {
            STAGE(cur, tt + 2)
            asm volatile("s_waitcnt vmcnt(%0)" :: "n"(LPT) : "memory");  // tile tt+1 landed
        } else if (tt + 1 < NT) {
            asm volatile("s_waitcnt vmcnt(0)" ::: "memory");
        }
        BAR;

        // last phase: prefetch next tile's subtile 0 (from landed buf cur^1); compute last subtile
        if (tt + 1 < NT) {
            LDA(afA, pAn, 0, 0)
            LDB(bf0, pBn, 0)
        }
        BAR;
        if (BN == 256) { MMA(4, afB, bf1) }
        else           { MMA(0, afB, bf1) }
        BAR;
        cur ^= 1;
    }
#undef STAGE
#undef LDA
#undef LDB
#undef MMA

    // epilogue: C/D layout col=lane&15, row=(lane>>4)*4+reg
#pragma unroll
    for (int m = 0; m < MR; m++)
#pragma unroll
        for (int n = 0; n < 4; n++) {
            const int row0 = m0 + wr * (MR * 16) + m * 16 + lc * 4;
            const int col = n0 + wc * 64 + n * 16 + lr;
            float v[4];
#pragma unroll
            for (int r = 0; r < 4; r++) {
                v[r] = acc[m][n][r];
                if (bias) v[r] += bias[col] * bscale;
                if (relu) v[r] = fmaxf(v[r], 0.0f);
            }
            if (VtOut && col >= 2 * EE) {
                // V block: write transposed (vt[d][s]), 4 consecutive rows = 8B store
                f16x4 h4;
#pragma unroll
                for (int r = 0; r < 4; r++) h4[r] = (f16)v[r];
                *(f16x4*)&VtOut[(size_t)(col - 2 * EE) * SS + row0] = h4;
            } else if (Ch) {
#pragma unroll
                for (int r = 0; r < 4; r++)
                    Ch[(size_t)(row0 + r) * N + col] = (f16)v[r];
            } else {
#pragma unroll
                for (int r = 0; r < 4; r++)
                    Cfb[(size_t)(row0 + r) * N + col] = v[r] * oscale;
            }
        }
}

// ---------------- flash attention (counted-vmcnt pipeline) ----------------
__global__ __launch_bounds__(256) void k_flash(
    const f16* __restrict__ qkv, const f16* __restrict__ vt, f16* __restrict__ attn) {
    __shared__ f16 Ks[2][4096];
    __shared__ f16 Vs[2][4096];
    __shared__ f16 Ps[4096];
    const int h = blockIdx.x;
    const int qb = blockIdx.y;
    const int t = threadIdx.x, l = t & 63, w = t >> 6;
    const int lr = l & 15, lc = l >> 4;
    const int q0 = qb * 64;
    const int qrow = q0 + w * 16 + lr;

    f16x8 qf0 = *(const f16x8*)&qkv[(size_t)qrow * 3072 + h * 64 + lc * 8];
    f16x8 qf1 = *(const f16x8*)&qkv[(size_t)qrow * 3072 + h * 64 + 32 + lc * 8];

    f32x4 o[4] = {};
    float mrun[4], lrun[4];
#pragma unroll
    for (int r = 0; r < 4; r++) { mrun[r] = -__builtin_inff(); lrun[r] = 0.0f; }

    const int krow = t >> 3;
    const int kscol = 8 * ((t & 7) ^ (krow & 7));
    const f16* gK = qkv + EE + h * 64;
    const f16* gV = vt + (size_t)(h * 64) * SS;
    f16* Pw = &Ps[w * 16 * 64];
    const int psw = (lr & 7) << 4;

#define FSTAGE(bb, kt_) { \
    char* dK = (char*)Ks[bb] + w * 1024; \
    char* dV = (char*)Vs[bb] + w * 1024; \
    gload16(gK + (size_t)((kt_) * 64 + krow) * 3072 + kscol, dK); \
    gload16(gK + (size_t)((kt_) * 64 + krow + 32) * 3072 + kscol, dK + 4096); \
    gload16(gV + (size_t)krow * SS + (kt_) * 64 + kscol, dV); \
    gload16(gV + (size_t)(krow + 32) * SS + (kt_) * 64 + kscol, dV + 4096); }

    const int nkt = qb + 1;
    FSTAGE(0, 0)
    FSTAGE(1, 1)
    asm volatile("s_waitcnt vmcnt(4)" ::: "memory");
    __builtin_amdgcn_s_barrier();

    int cur = 0;
    for (int kt = 0; kt < nkt; kt++) {
        f32x4 sc[4];
        __builtin_amdgcn_s_setprio(1);
#pragma unroll
        for (int kj = 0; kj < 4; kj++) {
            const int krw = kj * 16 + lr;
            const int sw = krw & 7;
            f16x8 kb0 = *(const f16x8*)&Ks[cur][krw * 64 + 8 * (lc ^ sw)];
            f16x8 kb1 = *(const f16x8*)&Ks[cur][krw * 64 + 8 * ((lc + 4) ^ sw)];
            f32x4 z = {};
            z = __builtin_amdgcn_mfma_f32_16x16x32_f16(qf0, kb0, z, 0, 0, 0);
            z = __builtin_amdgcn_mfma_f32_16x16x32_f16(qf1, kb1, z, 0, 0, 0);
            sc[kj] = z;
        }
        __builtin_amdgcn_s_setprio(0);

        const bool diag = (kt == qb);
#pragma unroll
        for (int kj = 0; kj < 4; kj++)
#pragma unroll
            for (int r = 0; r < 4; r++) {
                float v = sc[kj][r] * SCORE_SCALE;
                if (diag) {
                    int qq = w * 16 + lc * 4 + r;
                    int kk = kj * 16 + lr;
                    if (kk > qq) v = -__builtin_inff();
                }
                sc[kj][r] = v;
            }

#pragma unroll
        for (int r = 0; r < 4; r++) {
            float mt = fmaxf(fmaxf(sc[0][r], sc[1][r]), fmaxf(sc[2][r], sc[3][r]));
            mt = fmaxf(mt, __shfl_xor(mt, 1));
            mt = fmaxf(mt, __shfl_xor(mt, 2));
            mt = fmaxf(mt, __shfl_xor(mt, 4));
            mt = fmaxf(mt, __shfl_xor(mt, 8));
            float mnew = fmaxf(mrun[r], mt);
            float alpha = __expf(mrun[r] - mnew);
            float psum = 0.0f;
#pragma unroll
            for (int kj = 0; kj < 4; kj++) {
                float p = __expf(sc[kj][r] - mnew);
                sc[kj][r] = p;
                psum += p;
            }
            psum += __shfl_xor(psum, 1);
            psum += __shfl_xor(psum, 2);
            psum += __shfl_xor(psum, 4);
            psum += __shfl_xor(psum, 8);
            lrun[r] = lrun[r] * alpha + psum;
            mrun[r] = mnew;
#pragma unroll
            for (int dj = 0; dj < 4; dj++) o[dj][r] *= alpha;
        }

#pragma unroll
        for (int kj = 0; kj < 4; kj++)
#pragma unroll
            for (int r = 0; r < 4; r++) {
                int prow = lc * 4 + r;
                int pb = prow * 128 + ((kj * 16 + lr) * 2 ^ ((prow & 7) << 4));
                *(f16*)((char*)Pw + pb) = (f16)sc[kj][r];
            }

        __builtin_amdgcn_s_setprio(1);
#pragma unroll
        for (int s2 = 0; s2 < 2; s2++) {
            f16x8 pa = *(const f16x8*)((const char*)Pw + lr * 128 + (((lc + 4 * s2) * 16) ^ psw));
#pragma unroll
            for (int dj = 0; dj < 4; dj++) {
                const int vrow = dj * 16 + lr;
                f16x8 vb = *(const f16x8*)&Vs[cur][vrow * 64 + 8 * ((lc + 4 * s2) ^ (vrow & 7))];
                o[dj] = __builtin_amdgcn_mfma_f32_16x16x32_f16(pa, vb, o[dj], 0, 0, 0);
            }
        }
        __builtin_amdgcn_s_setprio(0);

        asm volatile("" ::: "memory");
        __builtin_amdgcn_s_barrier();
        if (kt + 2 < nkt) {
            FSTAGE(cur, kt + 2)
            asm volatile("s_waitcnt vmcnt(4)" ::: "memory");
        } else if (kt + 1 < nkt) {
            asm volatile("s_waitcnt vmcnt(0)" ::: "memory");
        }
        __builtin_amdgcn_s_barrier();
        cur ^= 1;
    }
#undef FSTAGE

#pragma unroll
    for (int dj = 0; dj < 4; dj++)
#pragma unroll
        for (int r = 0; r < 4; r++) {
            float v = o[dj][r] / lrun[r];
            attn[(size_t)(q0 + w * 16 + lc * 4 + r) * EE + h * 64 + dj * 16 + lr] = (f16)v;
        }
}

// ---------------- host launch ----------------
extern "C" void kernel_launch(void* const* d_in, const int* in_sizes, int n_in,
                              void* d_out, int out_size, void* d_ws, size_t ws_size,
                              hipStream_t stream) {
    const int*   ids  = (const int*)d_in[0];
    const float* emb  = (const float*)d_in[2];
    const float* Wq   = (const float*)d_in[3];
    const float* bq   = (const float*)d_in[4];
    const float* Wk   = (const float*)d_in[5];
    const float* bk   = (const float*)d_in[6];
    const float* Wv   = (const float*)d_in[7];
    const float* bv   = (const float*)d_in[8];
    const float* W1   = (const float*)d_in[9];
    const float* b1   = (const float*)d_in[10];
    const float* W2   = (const float*)d_in[11];
    const float* b2   = (const float*)d_in[12];
    const float* Wout = (const float*)d_in[13];
    float* out = (float*)d_out;

    char* p = (char*)d_ws;
    f16* xh    = (f16*)p; p += (size_t)SS * EE * 2;        // 4 MB
    f16* qkvh  = (f16*)p; p += (size_t)SS * 3 * EE * 2;    // 12 MB
    f16* vt    = (f16*)p; p += (size_t)EE * SS * 2;        // 4 MB
    f16* attn  = (f16*)p; p += (size_t)SS * EE * 2;        // 4 MB
    f16* h1    = (f16*)p; p += (size_t)SS * FF * 2;        // 16 MB
    f16* wqkvt = (f16*)p; p += (size_t)3 * EE * EE * 2;    // 6 MB
    f16* w1t   = (f16*)p; p += (size_t)FF * EE * 2;        // 8 MB
    f16* w2t   = (f16*)p; p += (size_t)EE * FF * 2;        // 8 MB
    f16* woutt = (f16*)p; p += (size_t)NV * EE * 2;        // 64 MB
    float* part = (float*)p; p += (size_t)4 * SS * EE * 4; // 32 MB
    float* bqkv = (float*)p; p += 3 * EE * 4;

    dim3 b32(32, 32);

    k_embed<<<SS, 256, 0, stream>>>(ids, emb, xh);

    for (int l = 0; l < NL; l++) {
        k_transpose_fused<<<11265, b32, 0, stream>>>(
            Wq + (size_t)l * EE * EE, Wk + (size_t)l * EE * EE, Wv + (size_t)l * EE * EE,
            W1 + (size_t)l * EE * FF, W2 + (size_t)l * FF * EE,
            bq + l * EE, bk + l * EE, bv + l * EE,
            wqkvt, w1t, w2t, bqkv);

        // QKV: [2048,1024] x [3072,1024]^T -> qkvh (Q,K) + vt (V transposed). grid 8*24=192
        k_gemm256<128><<<8 * 24, 512, 0, stream>>>(
            xh, wqkvt, bqkv, qkvh, nullptr, vt, SS, 3 * EE, EE, EE, 8, 24, 1, CS, 1.0f, 0);

        k_flash<<<dim3(NH, SS / 64), 256, 0, stream>>>(qkvh, vt, attn);

        // FFN1 + relu: [2048,1024] x [4096,1024]^T -> h1. grid 8*32=256
        k_gemm256<128><<<8 * 32, 512, 0, stream>>>(
            attn, w1t, b1 + (size_t)l * FF, h1, nullptr, nullptr, SS, FF, EE, EE, 8, 32, 1, CS, 1.0f, 1);

        // FFN2 split-K=4: [2048,4096] x [1024,4096]^T -> fp32 partials. grid 8*8*4=256
        k_gemm256<128><<<8 * 8 * 4, 512, 0, stream>>>(
            h1, w2t, nullptr, nullptr, part, nullptr, SS, EE, FF, FF / 4, 8, 8, 4, 0.0f, 1.0f, 0);
        k_combine4<<<SS * EE / 1024, 256, 0, stream>>>(part, b2 + (size_t)l * EE, xh);
    }

    // logits: [2048,1024] x [32000,1024]^T -> fp32 out. BN=256 grid 8*125=1000
    k_transpose_f32_f16<<<dim3(NV / 32, EE / 32), b32, 0, stream>>>(Wout, woutt, NV, EE);
    k_gemm256<256><<<8 * 125, 512, 0, stream>>>(
        xh, woutt, nullptr, nullptr, out, nullptr, SS, NV, EE, EE, 8, 125, 1, 0.0f, INV_CS, 0);
}